// Round 1
// 445.507 us; speedup vs baseline: 1.0117x; 1.0117x over previous
//
#include <hip/hip_runtime.h>
#include <stdint.h>
#include <stddef.h>

typedef __bf16 bf16x8 __attribute__((ext_vector_type(8)));
typedef float floatx4 __attribute__((ext_vector_type(4)));
typedef unsigned short u16;

__device__ __forceinline__ float bf2f(u16 h) {
    unsigned u = ((unsigned)h) << 16;
    return __builtin_bit_cast(float, u);
}
__device__ __forceinline__ u16 f2bf(float f) {
    unsigned u = __builtin_bit_cast(unsigned, f);
    u += 0x7fffu + ((u >> 16) & 1u);   // round-to-nearest-even
    return (u16)(u >> 16);
}

// async global->LDS, 16B per lane; lds dest is wave-uniform base (+lane*16 implicit)
__device__ __forceinline__ void gload16(const void* g, void* l) {
    __builtin_amdgcn_global_load_lds(
        (const __attribute__((address_space(1))) uint32_t*)g,
        (__attribute__((address_space(3))) uint32_t*)l, 16, 0, 0);
}

// ---------------- x: f32 -> bf16, vectorized (8/thread) ----------------
__global__ __launch_bounds__(256) void k_conv_x(const float* __restrict__ in,
                                                u16* __restrict__ out, int n8) {
    int i = blockIdx.x * 256 + threadIdx.x;
    if (i >= n8) return;
    const float* f = in + (size_t)i * 8;
    unsigned o[4];
    for (int t = 0; t < 4; t++) {
        u16 lo = f2bf(f[2 * t]), hi = f2bf(f[2 * t + 1]);
        o[t] = (unsigned)lo | ((unsigned)hi << 16);
    }
    uint4 p = {o[0], o[1], o[2], o[3]};
    *(uint4*)&out[(size_t)i * 8] = p;
}

// ---------------- weight: f32 (K,N) -> bf16 transposed (Npad,K), zero pad ----------------
__global__ __launch_bounds__(256) void k_convT(const float* __restrict__ in,
                                               u16* __restrict__ out, int K, int N) {
    __shared__ u16 t[32][33];
    int k0 = blockIdx.x * 32, n0 = blockIdx.y * 32;
    int c = threadIdx.x & 31, r8 = threadIdx.x >> 5;
    for (int j = 0; j < 4; j++) {
        int row = r8 + j * 8;
        int n = n0 + c;
        t[row][c] = (n < N) ? f2bf(in[(size_t)(k0 + row) * N + n]) : (u16)0;
    }
    __syncthreads();
    for (int j = 0; j < 4; j++) {
        int row = r8 + j * 8;
        out[(size_t)(n0 + row) * K + k0 + c] = t[c][row];
    }
}

// ---------------- V transpose: kv(b*S, h*256+128+vd) -> vt[(b,h,vd), s] ----------------
__global__ __launch_bounds__(256) void k_transpose_v(const u16* __restrict__ kv,
                                                     u16* __restrict__ vt) {
    __shared__ u16 t[32][33];
    int bh = blockIdx.z;
    int s0 = blockIdx.x * 32, v0 = blockIdx.y * 32;
    int c = threadIdx.x & 31, r8 = threadIdx.x >> 5;
    int b = bh >> 4, h = bh & 15;
    for (int j = 0; j < 4; j++) {
        int s = s0 + r8 + j * 8;
        t[r8 + j * 8][c] = kv[(size_t)(b * 2048 + s) * 4096 + h * 256 + 128 + v0 + c];
    }
    __syncthreads();
    for (int j = 0; j < 4; j++) {
        int v = v0 + r8 + j * 8;
        vt[((size_t)bh * 128 + v) * 2048 + s0 + c] = t[c][r8 + j * 8];
    }
}

// ---------------- legacy MFMA GEMM (m97 structure) — kept for small/ragged N (GEMM2) ----------------
template <bool F32OUT>
__global__ __launch_bounds__(256) void k_gemm_bt(const u16* __restrict__ A,
                                                 const u16* __restrict__ BT,
                                                 void* __restrict__ Cout,
                                                 int N, int K, int ldc) {
    __shared__ __align__(16) u16 As[128 * 32];
    __shared__ __align__(16) u16 Bs[128 * 32];
    int tid = threadIdx.x;
    int lane = tid & 63, wave = tid >> 6;
    int quad = lane >> 4, l15 = lane & 15;
    size_t m0 = (size_t)blockIdx.x * 128, n0 = (size_t)blockIdx.y * 128;
    int wm = (wave >> 1) * 64, wn = (wave & 1) * 64;
    const floatx4 fzero = {0.f, 0.f, 0.f, 0.f};
    floatx4 acc[4][4];
    for (int i = 0; i < 4; i++)
        for (int j = 0; j < 4; j++) acc[i][j] = fzero;

    for (int k0 = 0; k0 < K; k0 += 32) {
        for (int i = 0; i < 2; i++) {
            int cid = i * 256 + wave * 64 + lane;
            int row = cid >> 2, kc = cid & 3;
            gload16(&A[(m0 + row) * K + k0 + kc * 8], &As[(size_t)(i * 256 + wave * 64) * 8]);
            gload16(&BT[(n0 + row) * K + k0 + kc * 8], &Bs[(size_t)(i * 256 + wave * 64) * 8]);
        }
        __syncthreads();
        bf16x8 af[4], bfr[4];
        for (int i = 0; i < 4; i++) af[i]  = *(const bf16x8*)&As[(wm + i * 16 + l15) * 32 + quad * 8];
        for (int j = 0; j < 4; j++) bfr[j] = *(const bf16x8*)&Bs[(wn + j * 16 + l15) * 32 + quad * 8];
        for (int i = 0; i < 4; i++)
            for (int j = 0; j < 4; j++)
                acc[i][j] = __builtin_amdgcn_mfma_f32_16x16x32_bf16(af[i], bfr[j], acc[i][j], 0, 0, 0);
        __syncthreads();
    }
    for (int i = 0; i < 4; i++)
        for (int j = 0; j < 4; j++) {
            int col = (int)n0 + wn + j * 16 + l15;
            if (col >= N) continue;
            for (int r = 0; r < 4; r++) {
                size_t row = m0 + wm + i * 16 + quad * 4 + r;
                if (F32OUT) ((float*)Cout)[row * ldc + col] = acc[i][j][r];
                else        ((u16*)Cout)[row * ldc + col] = f2bf(acc[i][j][r]);
            }
        }
}

// ---------------- 256x256 8-phase GEMM (T2+T3+T4+T5): C = A * BT^T ----------------
// BM=BN=256, BK=64, 512 thr = 8 waves (wr=w>>2 -> 128 rows, wc=w&3 -> 64 cols).
// LDS 128 KiB: 2-deep dbuf of A(256x64) + B(256x64) bf16, stored as 1 KiB subtiles
// [R=row>>4][C=k>>5] with st_16x32 swizzle (u16idx ^= (r>>3)<<4) inside each subtile.
// global_load_lds writes LINEARLY; swizzle realized by inverse-swizzling the per-lane
// GLOBAL source address (rule #21: both-sides-or-neither).
// Per tile: 4 quadrant phases {ds_read frags | 2 stage-slot gload_lds | s_barrier |
// setprio(1) 16xMFMA setprio(0) | s_barrier}; ONE vmcnt(0) drain per tile (the
// boundary __syncthreads) — prefetched loads ride 1-4 phases in flight across the
// raw per-phase barriers (counted-vmcnt effect without per-phase drains).
// Requires: M%256==0, N%256==0, K%128==0 (NT even). All call sites satisfy this.
template <bool F32OUT>
__global__ __launch_bounds__(512, 2) void k_gemm256(const u16* __restrict__ A,
                                                    const u16* __restrict__ BT,
                                                    void* __restrict__ Cout,
                                                    int K, int ldc) {
    __shared__ __align__(16) u16 LA[2][16384];
    __shared__ __align__(16) u16 LB[2][16384];
    int tid = threadIdx.x;
    int w = tid >> 6, lane = tid & 63;
    int l15 = lane & 15, quad = lane >> 4;
    int wr = w >> 2, wc = w & 3;
    size_t m0 = (size_t)blockIdx.x * 256, n0 = (size_t)blockIdx.y * 256;
    int NT = K >> 6;

    // --- staging: slot p (p=0..3) = chunks [p*512, p*512+512); this thread's chunk:
    // chunk_id = p*512 + w*64 + lane -> fills subtile s = p*8 + w, u16-in-subtile = lane*8.
    // Unswizzle to find which global (row,k) element lives at that linear LDS spot.
    const u16* srcA[4];
    const u16* srcB[4];
    int ldsOff[4];
#pragma unroll
    for (int p = 0; p < 4; p++) {
        int chunk = p * 512 + w * 64 + lane;
        int u16off = chunk * 8;
        int s = u16off >> 9;                       // subtile index 0..31
        int b = u16off & 511;
        int bu = b ^ (((b >> 8) & 1) << 4);        // inverse st_16x32 swizzle (involution)
        int r = bu >> 5, c = bu & 31;
        int row = (s >> 1) * 16 + r;
        int k = (s & 1) * 32 + c;
        srcA[p] = A + (m0 + row) * (size_t)K + k;
        srcB[p] = BT + (n0 + row) * (size_t)K + k;
        ldsOff[p] = (p * 512 + w * 64) * 8;        // linear wave base (u16)
    }

    // --- ds_read lane offset inside a subtile (swizzled) ---
    const int swb = (l15 * 32 + quad * 8) ^ ((l15 >> 3) << 4);

    floatx4 acc[8][4];
    const floatx4 fzero = {0.f, 0.f, 0.f, 0.f};
#pragma unroll
    for (int i = 0; i < 8; i++)
#pragma unroll
        for (int j = 0; j < 4; j++) acc[i][j] = fzero;

    bf16x8 aA[4][2], bB[2][2];

    auto SLOT = [&](int nxt, int p, int t) {
        size_t ko = (size_t)t * 64;
        gload16(srcA[p] + ko, &LA[nxt][ldsOff[p]]);
        gload16(srcB[p] + ko, &LB[nxt][ldsOff[p]]);
    };
    auto LDA_ = [&](int cur, int ih) {
#pragma unroll
        for (int i2 = 0; i2 < 4; i2++)
#pragma unroll
            for (int ks = 0; ks < 2; ks++)
                aA[i2][ks] = *(const bf16x8*)&LA[cur][((wr * 8 + ih * 4 + i2) * 2 + ks) * 512 + swb];
    };
    auto LDB_ = [&](int cur, int jh) {
#pragma unroll
        for (int j2 = 0; j2 < 2; j2++)
#pragma unroll
            for (int ks = 0; ks < 2; ks++)
                bB[j2][ks] = *(const bf16x8*)&LB[cur][((wc * 4 + jh * 2 + j2) * 2 + ks) * 512 + swb];
    };
    auto MMA = [&](int ih, int jh) {
        __builtin_amdgcn_s_setprio(1);
#pragma unroll
        for (int i2 = 0; i2 < 4; i2++)
#pragma unroll
            for (int j2 = 0; j2 < 2; j2++)
#pragma unroll
                for (int ks = 0; ks < 2; ks++)
                    acc[ih * 4 + i2][jh * 2 + j2] = __builtin_amdgcn_mfma_f32_16x16x32_bf16(
                        aA[i2][ks], bB[j2][ks], acc[ih * 4 + i2][jh * 2 + j2], 0, 0, 0);
        __builtin_amdgcn_s_setprio(0);
    };

    // prologue: stage tile 0 -> buf0, full drain
#pragma unroll
    for (int p = 0; p < 4; p++) SLOT(0, p, 0);
    __syncthreads();

    auto TILE = [&](int cur, int tnext, bool have) {
        int nxt = cur ^ 1;
        // phase 0: quadrant (0,0)
        LDA_(cur, 0); LDB_(cur, 0);
        if (have) SLOT(nxt, 0, tnext);
        __builtin_amdgcn_s_barrier();
        MMA(0, 0);
        __builtin_amdgcn_s_barrier();
        // phase 1: quadrant (0,1) — reuse aA
        LDB_(cur, 1);
        if (have) SLOT(nxt, 1, tnext);
        __builtin_amdgcn_s_barrier();
        MMA(0, 1);
        __builtin_amdgcn_s_barrier();
        // phase 2: quadrant (1,1) — reuse bB
        LDA_(cur, 1);
        if (have) SLOT(nxt, 2, tnext);
        __builtin_amdgcn_s_barrier();
        MMA(1, 1);
        __builtin_amdgcn_s_barrier();
        // phase 3: quadrant (1,0)
        LDB_(cur, 0);
        if (have) SLOT(nxt, 3, tnext);
        __builtin_amdgcn_s_barrier();
        MMA(1, 0);
        // tile boundary: single drain (vmcnt(0)+lgkmcnt(0)+barrier) — next tile reads nxt
        __syncthreads();
    };

    for (int t = 0; t < NT; t += 2) {
        TILE(0, t + 1, true);
        TILE(1, t + 2, t + 2 < NT);
    }

#pragma unroll
    for (int i = 0; i < 8; i++)
#pragma unroll
        for (int j = 0; j < 4; j++) {
            size_t col = n0 + wc * 64 + j * 16 + l15;
#pragma unroll
            for (int r = 0; r < 4; r++) {
                size_t row = m0 + wr * 128 + i * 16 + quad * 4 + r;
                if (F32OUT) ((float*)Cout)[row * ldc + col] = acc[i][j][r];
                else        ((u16*)Cout)[row * ldc + col] = f2bf(acc[i][j][r]);
            }
        }
}

// ---------------- RMSNorm over first 512 cols of kva rows -> ckv ----------------
__global__ __launch_bounds__(64) void k_rmsnorm(const u16* __restrict__ kva,
                                                const float* __restrict__ scl,
                                                u16* __restrict__ ckv) {
    int r = blockIdx.x, lane = threadIdx.x;
    const u16* row = kva + (size_t)r * 576 + lane * 8;
    uint4 raw = *(const uint4*)row;
    unsigned w[4] = {raw.x, raw.y, raw.z, raw.w};
    float f[8];
    float ss = 0.f;
    for (int t = 0; t < 4; t++) {
        f[2 * t]     = bf2f((u16)(w[t] & 0xffffu));
        f[2 * t + 1] = bf2f((u16)(w[t] >> 16));
        ss += f[2 * t] * f[2 * t] + f[2 * t + 1] * f[2 * t + 1];
    }
    for (int off = 1; off < 64; off <<= 1) ss += __shfl_xor(ss, off, 64);
    float rs = rsqrtf(ss * (1.f / 512.f) + 1e-6f);
    unsigned o[4];
    for (int t = 0; t < 4; t++) {
        u16 lo = f2bf(f[2 * t] * rs * scl[lane * 8 + 2 * t]);
        u16 hi = f2bf(f[2 * t + 1] * rs * scl[lane * 8 + 2 * t + 1]);
        o[t] = (unsigned)lo | ((unsigned)hi << 16);
    }
    uint4 packed = {o[0], o[1], o[2], o[3]};
    *(uint4*)(ckv + (size_t)r * 512 + lane * 8) = packed;
}

// ---------------- RoPE in-place ----------------
__global__ __launch_bounds__(256) void k_rope(u16* __restrict__ qbuf, u16* __restrict__ kva) {
    int r = blockIdx.x;
    int s = r & 2047;
    for (int t = threadIdx.x; t < 544; t += 256) {
        int i = t & 31;
        float freq = powf(10000.f, -2.f * (float)i / 64.f);
        float ang = (float)s * freq;
        float sn, cs;
        sincosf(ang, &sn, &cs);
        u16* p1;
        if (t < 512) {
            int h = t >> 5;
            p1 = qbuf + (size_t)r * 3072 + h * 192 + 128 + i;
        } else {
            p1 = kva + (size_t)r * 576 + 512 + i;
        }
        u16* p2 = p1 + 32;
        float x1 = bf2f(*p1), x2 = bf2f(*p2);
        *p1 = f2bf(x1 * cs - x2 * sn);
        *p2 = f2bf(x2 * cs + x1 * sn);
    }
}

// ---------------- Flash attention v3.1: block-cooperative, double-buffered LDS K/V ----------------
__global__ __launch_bounds__(256, 3) void k_attn(const u16* __restrict__ qbuf,
                                                 const u16* __restrict__ kv,
                                                 const u16* __restrict__ kva,
                                                 const u16* __restrict__ vt,
                                                 u16* __restrict__ attno) {
    int tid = threadIdx.x;
    int wave = tid >> 6, lane = tid & 63;
    int quad = lane >> 4, l15 = lane & 15;
    int hb = blockIdx.x;                 // 0..31
    int h = hb & 15, b = hb >> 4;
    int qb = 31 - (int)blockIdx.y;       // descending: longest blocks first
    int qg0 = qb * 64 + wave * 16;       // wave's first q-row
    int row = qg0 + l15;                 // this lane's q-row (S^T col)

    __shared__ __align__(16) u16 Kn[2][32 * 136];
    __shared__ __align__(16) u16 Kp[2][32 * 72];
    __shared__ __align__(16) u16 Vs[2][128 * 40];
    __shared__ __align__(16) u16 P[4][16 * 40];

    const u16* qrp = qbuf + ((size_t)(b * 2048) + qg0 + l15) * 3072 + h * 192;
    bf16x8 qf[6];
    for (int c = 0; c < 6; c++) qf[c] = *(const bf16x8*)&qrp[c * 32 + quad * 8];

    const floatx4 fzero = {0.f, 0.f, 0.f, 0.f};
    floatx4 o[8];
    for (int f = 0; f < 8; f++) o[f] = fzero;
    float lp = 0.f;

    const u16* kvb = kv  + (size_t)(b * 2048) * 4096 + h * 256;   // + key*4096 (k_nope)
    const u16* kpb = kva + (size_t)(b * 2048) * 576 + 512;        // + key*576  (roped k_pe)
    const u16* vtb = vt  + (size_t)(b * 16 + h) * 128 * 2048;     // + vd*2048 + key
    const float scale = 0.07216878364870323f;                     // 192^-0.5

    int nkt = qb * 2 + 2;                // ceil((qb*64+63+1)/32)

    // staging chunk maps (16B chunks)
    int kKey0 = tid >> 4,          kOff0 = (tid & 15) * 8;        // Kn: 16 chunks/row
    int kKey1 = (tid + 256) >> 4,  kOff1 = (tid & 15) * 8;
    int pKey  = tid >> 3,          pOff  = (tid & 7) * 8;         // Kp: 8 chunks/row
    int vRow0 = tid >> 2,          vOff0 = (tid & 3) * 8;         // Vs: 4 chunks/row (rows 0..63)
    int vRow1 = (tid + 256) >> 2,  vOff1 = (tid & 3) * 8;         //     rows 64..127

    // prologue: stage tile 0 into buffer 0
    {
        uint4 a = *(const uint4*)&kvb[(size_t)kKey0 * 4096 + kOff0];
        uint4 c = *(const uint4*)&kvb[(size_t)kKey1 * 4096 + kOff1];
        uint4 d = *(const uint4*)&kpb[(size_t)pKey * 576 + pOff];
        uint4 e = *(const uint4*)&vtb[(size_t)vRow0 * 2048 + vOff0];
        uint4 g = *(const uint4*)&vtb[(size_t)vRow1 * 2048 + vOff1];
        *(uint4*)&Kn[0][kKey0 * 136 + kOff0] = a;
        *(uint4*)&Kn[0][kKey1 * 136 + kOff1] = c;
        *(uint4*)&Kp[0][pKey * 72 + pOff] = d;
        *(uint4*)&Vs[0][vRow0 * 40 + vOff0] = e;
        *(uint4*)&Vs[0][vRow1 * 40 + vOff1] = g;
    }
    __syncthreads();

    for (int kt = 0; kt < nkt; kt++) {
        int cur = kt & 1;
        bool have = (kt + 1) < nkt;
        uint4 sA = {}, sB = {}, sC = {}, sD = {}, sE = {};
        if (have) {
            int kb = (kt + 1) * 32;
            sA = *(const uint4*)&kvb[(size_t)(kb + kKey0) * 4096 + kOff0];
            sB = *(const uint4*)&kvb[(size_t)(kb + kKey1) * 4096 + kOff1];
            sC = *(const uint4*)&kpb[(size_t)(kb + pKey) * 576 + pOff];
            sD = *(const uint4*)&vtb[(size_t)vRow0 * 2048 + kb + vOff0];
            sE = *(const uint4*)&vtb[(size_t)vRow1 * 2048 + kb + vOff1];
        }
        if (kt * 32 <= qg0 + 15) {       // tile intersects this wave's causal range
            bf16x8 vf[8];
            for (int f = 0; f < 8; f++)
                vf[f] = *(const bf16x8*)&Vs[cur][(f * 16 + l15) * 40 + quad * 8];
            floatx4 sc[2] = {fzero, fzero};
            for (int hf = 0; hf < 2; hf++) {
                const u16* kn = &Kn[cur][(hf * 16 + l15) * 136];
                const u16* kp = &Kp[cur][(hf * 16 + l15) * 72];
                for (int c = 0; c < 4; c++) {
                    bf16x8 kf = *(const bf16x8*)&kn[c * 32 + quad * 8];
                    sc[hf] = __builtin_amdgcn_mfma_f32_16x16x32_bf16(kf, qf[c], sc[hf], 0, 0, 0);
                }
                for (int c = 0; c < 2; c++) {
                    bf16x8 kf = *(const bf16x8*)&kp[c * 32 + quad * 8];
                    sc[hf] = __builtin_amdgcn_mfma_f32_16x16x32_bf16(kf, qf[4 + c], sc[hf], 0, 0, 0);
                }
            }
            asm volatile("" ::: "memory");
            for (int hf = 0; hf < 2; hf++) {
                int keyb = kt * 32 + hf * 16 + quad * 4;
                float p[4];
                for (int r = 0; r < 4; r++)
                    p[r] = (keyb + r <= row) ? __expf(sc[hf][r] * scale) : 0.f;
                lp += (p[0] + p[1]) + (p[2] + p[3]);
                unsigned d0 = (unsigned)f2bf(p[0]) | ((unsigned)f2bf(p[1]) << 16);
                unsigned d1 = (unsigned)f2bf(p[2]) | ((unsigned)f2bf(p[3]) << 16);
                uint2 pk = {d0, d1};
                *(uint2*)&P[wave][l15 * 40 + hf * 16 + quad * 4] = pk;
            }
            asm volatile("" ::: "memory");
            bf16x8 pa = *(const bf16x8*)&P[wave][l15 * 40 + quad * 8];
            asm volatile("" ::: "memory");
            for (int f = 0; f < 8; f++)
                o[f] = __builtin_amdgcn_mfma_f32_16x16x32_bf16(pa, vf[f], o[f], 0, 0, 0);
        }
        if (have) {
            int nb = cur ^ 1;
            *(uint4*)&Kn[nb][kKey0 * 136 + kOff0] = sA;
            *(uint4*)&Kn[nb][kKey1 * 136 + kOff1] = sB;
            *(uint4*)&Kp[nb][pKey * 72 + pOff] = sC;
            *(uint4*)&Vs[nb][vRow0 * 40 + vOff0] = sD;
            *(uint4*)&Vs[nb][vRow1 * 40 + vOff1] = sE;
        }
        __syncthreads();
    }

    // reduce l across quads (lanes sharing l15 hold partials over key-quads)
    lp += __shfl_xor(lp, 16, 64);
    lp += __shfl_xor(lp, 32, 64);
    float lrow[4];
    for (int r = 0; r < 4; r++) lrow[r] = __shfl(lp, quad * 4 + r, 64);
    for (int f = 0; f < 8; f++)
        for (int r = 0; r < 4; r++) {
            int orow = qg0 + quad * 4 + r;
            float val = o[f][r] / lrow[r];
            attno[((size_t)(b * 2048) + orow) * 2048 + h * 128 + f * 16 + l15] = f2bf(val);
        }
}

extern "C" void kernel_launch(void* const* d_in, const int* in_sizes, int n_in,
                              void* d_out, int out_size, void* d_ws, size_t ws_size,
                              hipStream_t stream) {
    const float* x_raw    = (const float*)d_in[0];
    const float* wq_raw   = (const float*)d_in[1];
    const float* wkva_raw = (const float*)d_in[2];
    const float* wkvb_raw = (const float*)d_in[3];
    const float* wo_raw   = (const float*)d_in[4];
    const float* kvs_raw  = (const float*)d_in[5];
    float* out = (float*)d_out;
    u16* ws = (u16*)d_ws;

    // ---- ws regions (u16 offsets); total 96,993,280 bytes (< proven 105.4 MB) ----
    const size_t O_ATT = 0;          // wq_t -> {ckv, wkvb_t} -> attno
    const size_t O_VT  = 8388608;    // x_bf -> vt
    const size_t O_QB  = 16777216;   // qbuf -> wo_t
    const size_t O_KVA = 29360128;   // kva
    const size_t O_KV  = 31719424;   // kv
    const size_t TOTAL_BYTES = 48496640ull * 2;
    if (ws_size < TOTAL_BYTES) return;   // diagnostic: zeros -> absmax 4.03125

    u16* wq_t   = ws + O_ATT;
    u16* wkva_t = ws + O_ATT;            // after GEMM1
    u16* ckv    = ws + O_ATT;            // after GEMM2
    u16* wkvb_t = ws + O_ATT + 2097152;
    u16* attno  = ws + O_ATT;            // after GEMM3
    u16* x_bf   = ws + O_VT;
    u16* vt     = ws + O_VT;             // after GEMM2
    u16* qbuf   = ws + O_QB;
    u16* wo_t   = ws + O_QB;             // after attn
    u16* kva    = ws + O_KVA;
    u16* kv     = ws + O_KV;

    k_conv_x<<<4096, 256, 0, stream>>>(x_raw, x_bf, 1048576);
    k_convT<<<dim3(64, 96), 256, 0, stream>>>(wq_raw, wq_t, 2048, 3072);

    k_gemm256<false><<<dim3(16, 12), 512, 0, stream>>>(x_bf, wq_t, qbuf, 2048, 3072);         // GEMM1

    k_convT<<<dim3(64, 20), 256, 0, stream>>>(wkva_raw, wkva_t, 2048, 576);
    k_gemm_bt<false><<<dim3(32, 5), 256, 0, stream>>>(x_bf, wkva_t, kva, 576, 2048, 576);     // GEMM2

    k_rmsnorm<<<4096, 64, 0, stream>>>(kva, kvs_raw, ckv);
    k_convT<<<dim3(16, 128), 256, 0, stream>>>(wkvb_raw, wkvb_t, 512, 4096);
    k_gemm256<false><<<dim3(16, 16), 512, 0, stream>>>(ckv, wkvb_t, kv, 512, 4096);           // GEMM3

    k_rope<<<4096, 256, 0, stream>>>(qbuf, kva);
    k_transpose_v<<<dim3(64, 4, 32), 256, 0, stream>>>(kv, vt);

    k_attn<<<dim3(32, 32), 256, 0, stream>>>(qbuf, kv, kva, vt, attno);

    k_convT<<<dim3(64, 64), 256, 0, stream>>>(wo_raw, wo_t, 2048, 2048);
    k_gemm256<true><<<dim3(16, 8), 512, 0, stream>>>(attno, wo_t, out, 2048, 2048);           // GEMM4 -> f32
}

// Round 2
// 436.662 us; speedup vs baseline: 1.0322x; 1.0203x over previous
//
#include <hip/hip_runtime.h>
#include <stdint.h>
#include <stddef.h>

typedef __bf16 bf16x8 __attribute__((ext_vector_type(8)));
typedef float floatx4 __attribute__((ext_vector_type(4)));
typedef unsigned short u16;

__device__ __forceinline__ float bf2f(u16 h) {
    unsigned u = ((unsigned)h) << 16;
    return __builtin_bit_cast(float, u);
}
__device__ __forceinline__ u16 f2bf(float f) {
    unsigned u = __builtin_bit_cast(unsigned, f);
    u += 0x7fffu + ((u >> 16) & 1u);   // round-to-nearest-even
    return (u16)(u >> 16);
}

// async global->LDS, 16B per lane; lds dest is wave-uniform base (+lane*16 implicit)
__device__ __forceinline__ void gload16(const void* g, void* l) {
    __builtin_amdgcn_global_load_lds(
        (const __attribute__((address_space(1))) uint32_t*)g,
        (__attribute__((address_space(3))) uint32_t*)l, 16, 0, 0);
}

// ---------------- x: f32 -> bf16, vectorized (8/thread) ----------------
__global__ __launch_bounds__(256) void k_conv_x(const float* __restrict__ in,
                                                u16* __restrict__ out, int n8) {
    int i = blockIdx.x * 256 + threadIdx.x;
    if (i >= n8) return;
    const float* f = in + (size_t)i * 8;
    unsigned o[4];
    for (int t = 0; t < 4; t++) {
        u16 lo = f2bf(f[2 * t]), hi = f2bf(f[2 * t + 1]);
        o[t] = (unsigned)lo | ((unsigned)hi << 16);
    }
    uint4 p = {o[0], o[1], o[2], o[3]};
    *(uint4*)&out[(size_t)i * 8] = p;
}

// ---------------- weight: f32 (K,N) -> bf16 transposed (Npad,K), zero pad ----------------
__global__ __launch_bounds__(256) void k_convT(const float* __restrict__ in,
                                               u16* __restrict__ out, int K, int N) {
    __shared__ u16 t[32][33];
    int k0 = blockIdx.x * 32, n0 = blockIdx.y * 32;
    int c = threadIdx.x & 31, r8 = threadIdx.x >> 5;
    for (int j = 0; j < 4; j++) {
        int row = r8 + j * 8;
        int n = n0 + c;
        t[row][c] = (n < N) ? f2bf(in[(size_t)(k0 + row) * N + n]) : (u16)0;
    }
    __syncthreads();
    for (int j = 0; j < 4; j++) {
        int row = r8 + j * 8;
        out[(size_t)(n0 + row) * K + k0 + c] = t[c][row];
    }
}

// ---------------- V transpose: kv(b*S, h*256+128+vd) -> vt[(b,h,vd), s] ----------------
__global__ __launch_bounds__(256) void k_transpose_v(const u16* __restrict__ kv,
                                                     u16* __restrict__ vt) {
    __shared__ u16 t[32][33];
    int bh = blockIdx.z;
    int s0 = blockIdx.x * 32, v0 = blockIdx.y * 32;
    int c = threadIdx.x & 31, r8 = threadIdx.x >> 5;
    int b = bh >> 4, h = bh & 15;
    for (int j = 0; j < 4; j++) {
        int s = s0 + r8 + j * 8;
        t[r8 + j * 8][c] = kv[(size_t)(b * 2048 + s) * 4096 + h * 256 + 128 + v0 + c];
    }
    __syncthreads();
    for (int j = 0; j < 4; j++) {
        int v = v0 + r8 + j * 8;
        vt[((size_t)bh * 128 + v) * 2048 + s0 + c] = t[c][r8 + j * 8];
    }
}

// ---------------- legacy MFMA GEMM (m97 structure) — kept for small/ragged N (GEMM2) ----------------
template <bool F32OUT>
__global__ __launch_bounds__(256) void k_gemm_bt(const u16* __restrict__ A,
                                                 const u16* __restrict__ BT,
                                                 void* __restrict__ Cout,
                                                 int N, int K, int ldc) {
    __shared__ __align__(16) u16 As[128 * 32];
    __shared__ __align__(16) u16 Bs[128 * 32];
    int tid = threadIdx.x;
    int lane = tid & 63, wave = tid >> 6;
    int quad = lane >> 4, l15 = lane & 15;
    size_t m0 = (size_t)blockIdx.x * 128, n0 = (size_t)blockIdx.y * 128;
    int wm = (wave >> 1) * 64, wn = (wave & 1) * 64;
    const floatx4 fzero = {0.f, 0.f, 0.f, 0.f};
    floatx4 acc[4][4];
    for (int i = 0; i < 4; i++)
        for (int j = 0; j < 4; j++) acc[i][j] = fzero;

    for (int k0 = 0; k0 < K; k0 += 32) {
        for (int i = 0; i < 2; i++) {
            int cid = i * 256 + wave * 64 + lane;
            int row = cid >> 2, kc = cid & 3;
            gload16(&A[(m0 + row) * K + k0 + kc * 8], &As[(size_t)(i * 256 + wave * 64) * 8]);
            gload16(&BT[(n0 + row) * K + k0 + kc * 8], &Bs[(size_t)(i * 256 + wave * 64) * 8]);
        }
        __syncthreads();
        bf16x8 af[4], bfr[4];
        for (int i = 0; i < 4; i++) af[i]  = *(const bf16x8*)&As[(wm + i * 16 + l15) * 32 + quad * 8];
        for (int j = 0; j < 4; j++) bfr[j] = *(const bf16x8*)&Bs[(wn + j * 16 + l15) * 32 + quad * 8];
        for (int i = 0; i < 4; i++)
            for (int j = 0; j < 4; j++)
                acc[i][j] = __builtin_amdgcn_mfma_f32_16x16x32_bf16(af[i], bfr[j], acc[i][j], 0, 0, 0);
        __syncthreads();
    }
    for (int i = 0; i < 4; i++)
        for (int j = 0; j < 4; j++) {
            int col = (int)n0 + wn + j * 16 + l15;
            if (col >= N) continue;
            for (int r = 0; r < 4; r++) {
                size_t row = m0 + wm + i * 16 + quad * 4 + r;
                if (F32OUT) ((float*)Cout)[row * ldc + col] = acc[i][j][r];
                else        ((u16*)Cout)[row * ldc + col] = f2bf(acc[i][j][r]);
            }
        }
}

// ---------------- 256xBN 4-phase GEMM (T1+T2+T3/T4-lite+T5): C = A * BT^T ----------------
// BM=256, BN=NWC*64 (NWC=4 -> 256x256, 128 KiB LDS; NWC=2 -> 256x128, 96 KiB LDS).
// 512 thr = 8 waves; wave grid (8/NWC) M x NWC N; per-wave output (32*NWC) x 64.
// st_16x32 swizzle inside 1 KiB subtiles; global_load_lds writes LINEARLY, swizzle
// realized by inverse-swizzling the per-lane GLOBAL source (rule #21).
// R1 fix (the drain-stall): ALL of tile t+1's global_load_lds are issued at the TOP
// of tile t (sched_barrier-pinned), so they have ~4 MFMA phases to land before the
// single per-tile __syncthreads drain (2-phase-template discipline: stage BEFORE
// ds_read+MFMA, ONE vmcnt(0)+barrier per tile). Loads span all intra-tile phases.
// XCD-aware block swizzle (nwg % 8 == 0 at every call site).
template <int NWC, bool F32OUT>
__global__ __launch_bounds__(512, 2) void k_gemm256(const u16* __restrict__ A,
                                                    const u16* __restrict__ BT,
                                                    void* __restrict__ Cout,
                                                    int K, int ldc) {
    constexpr int BN = NWC * 64;
    constexpr int MFR = 2 * NWC;        // M fragments per wave (8 or 4)
    __shared__ __align__(16) u16 LA[2][16384];
    __shared__ __align__(16) u16 LB[2][NWC * 4096];
    int tid = threadIdx.x;
    int w = tid >> 6, lane = tid & 63;
    int l15 = lane & 15, quad = lane >> 4;
    int wr = w / NWC, wc = w % NWC;     // NWC power of 2 -> shifts

    // XCD-aware swizzle (bijective: nwg % 8 == 0)
    int gx = gridDim.x;
    int nwg = gx * gridDim.y;
    int flat = blockIdx.y * gx + blockIdx.x;
    int cpx = nwg >> 3;
    int swz = (flat & 7) * cpx + (flat >> 3);
    int bx = swz % gx, by = swz / gx;
    size_t m0 = (size_t)bx * 256, n0 = (size_t)by * BN;
    int NT = K >> 6;

    // staging maps: chunk = p*512 + w*64 + lane fills subtile s=p*8+w linearly;
    // unswizzle to find the global (row,k) whose element lives at that LDS spot.
    const u16* srcA[4];
    const u16* srcB[NWC];
    int ldsA[4], ldsB[NWC];
#pragma unroll
    for (int p = 0; p < 4; p++) {
        int chunk = p * 512 + w * 64 + lane;
        int u16off = chunk * 8;
        int s = u16off >> 9;
        int b = u16off & 511;
        int bu = b ^ (((b >> 8) & 1) << 4);        // inverse st_16x32 (involution)
        int r = bu >> 5, c = bu & 31;
        int row = (s >> 1) * 16 + r;
        int k = (s & 1) * 32 + c;
        srcA[p] = A + (m0 + row) * (size_t)K + k;
        ldsA[p] = (p * 512 + w * 64) * 8;
        if (p < NWC) {
            srcB[p] = BT + (n0 + row) * (size_t)K + k;
            ldsB[p] = (p * 512 + w * 64) * 8;
        }
    }

    // swizzled ds_read lane offset inside a subtile
    const int swb = (l15 * 32 + quad * 8) ^ ((l15 >> 3) << 4);

    floatx4 acc[MFR][4];
    const floatx4 fzero = {0.f, 0.f, 0.f, 0.f};
#pragma unroll
    for (int i = 0; i < MFR; i++)
#pragma unroll
        for (int j = 0; j < 4; j++) acc[i][j] = fzero;

    bf16x8 aA[NWC][2], bB[2][2];

    auto STAGE_ALL = [&](int nxt, int t) {
        size_t ko = (size_t)t * 64;
#pragma unroll
        for (int p = 0; p < 4; p++) gload16(srcA[p] + ko, &LA[nxt][ldsA[p]]);
#pragma unroll
        for (int p = 0; p < NWC; p++) gload16(srcB[p] + ko, &LB[nxt][ldsB[p]]);
        __builtin_amdgcn_sched_barrier(0);  // pin the issue early (don't sink past MFMAs)
    };
    auto LDA_ = [&](int cur, int ih) {
#pragma unroll
        for (int i2 = 0; i2 < NWC; i2++)
#pragma unroll
            for (int ks = 0; ks < 2; ks++)
                aA[i2][ks] = *(const bf16x8*)&LA[cur][((wr * MFR + ih * NWC + i2) * 2 + ks) * 512 + swb];
    };
    auto LDB_ = [&](int cur, int jh) {
#pragma unroll
        for (int j2 = 0; j2 < 2; j2++)
#pragma unroll
            for (int ks = 0; ks < 2; ks++)
                bB[j2][ks] = *(const bf16x8*)&LB[cur][((wc * 4 + jh * 2 + j2) * 2 + ks) * 512 + swb];
    };
    auto MMA = [&](int ih, int jh) {
        __builtin_amdgcn_s_setprio(1);
#pragma unroll
        for (int i2 = 0; i2 < NWC; i2++)
#pragma unroll
            for (int j2 = 0; j2 < 2; j2++)
#pragma unroll
                for (int ks = 0; ks < 2; ks++)
                    acc[ih * NWC + i2][jh * 2 + j2] = __builtin_amdgcn_mfma_f32_16x16x32_bf16(
                        aA[i2][ks], bB[j2][ks], acc[ih * NWC + i2][jh * 2 + j2], 0, 0, 0);
        __builtin_amdgcn_s_setprio(0);
    };

    // prologue: stage tile 0 -> buf0, full drain
    STAGE_ALL(0, 0);
    __syncthreads();

    auto TILE = [&](int cur, int tnext, bool have) {
        int nxt = cur ^ 1;
        if (have) STAGE_ALL(nxt, tnext);   // ALL prefetch issued up front
        LDA_(cur, 0); LDB_(cur, 0);
        __builtin_amdgcn_s_barrier();
        MMA(0, 0);
        __builtin_amdgcn_s_barrier();
        LDB_(cur, 1);
        __builtin_amdgcn_s_barrier();
        MMA(0, 1);
        __builtin_amdgcn_s_barrier();
        LDA_(cur, 1);
        __builtin_amdgcn_s_barrier();
        MMA(1, 1);
        __builtin_amdgcn_s_barrier();
        LDB_(cur, 0);
        __builtin_amdgcn_s_barrier();
        MMA(1, 0);
        // tile boundary: single vmcnt(0)+lgkmcnt(0)+barrier drain; prefetch had
        // the whole tile (~4 phases) to land, so this is cheap now.
        __syncthreads();
    };

    for (int t = 0; t < NT; t += 2) {
        TILE(0, t + 1, true);
        TILE(1, t + 2, t + 2 < NT);
    }

#pragma unroll
    for (int i = 0; i < MFR; i++)
#pragma unroll
        for (int j = 0; j < 4; j++) {
            size_t col = n0 + wc * 64 + j * 16 + l15;
#pragma unroll
            for (int r = 0; r < 4; r++) {
                size_t row = m0 + (size_t)wr * (32 * NWC) + i * 16 + quad * 4 + r;
                if (F32OUT) ((float*)Cout)[row * ldc + col] = acc[i][j][r];
                else        ((u16*)Cout)[row * ldc + col] = f2bf(acc[i][j][r]);
            }
        }
}

// ---------------- RMSNorm over first 512 cols of kva rows -> ckv ----------------
__global__ __launch_bounds__(64) void k_rmsnorm(const u16* __restrict__ kva,
                                                const float* __restrict__ scl,
                                                u16* __restrict__ ckv) {
    int r = blockIdx.x, lane = threadIdx.x;
    const u16* row = kva + (size_t)r * 576 + lane * 8;
    uint4 raw = *(const uint4*)row;
    unsigned w[4] = {raw.x, raw.y, raw.z, raw.w};
    float f[8];
    float ss = 0.f;
    for (int t = 0; t < 4; t++) {
        f[2 * t]     = bf2f((u16)(w[t] & 0xffffu));
        f[2 * t + 1] = bf2f((u16)(w[t] >> 16));
        ss += f[2 * t] * f[2 * t] + f[2 * t + 1] * f[2 * t + 1];
    }
    for (int off = 1; off < 64; off <<= 1) ss += __shfl_xor(ss, off, 64);
    float rs = rsqrtf(ss * (1.f / 512.f) + 1e-6f);
    unsigned o[4];
    for (int t = 0; t < 4; t++) {
        u16 lo = f2bf(f[2 * t] * rs * scl[lane * 8 + 2 * t]);
        u16 hi = f2bf(f[2 * t + 1] * rs * scl[lane * 8 + 2 * t + 1]);
        o[t] = (unsigned)lo | ((unsigned)hi << 16);
    }
    uint4 packed = {o[0], o[1], o[2], o[3]};
    *(uint4*)(ckv + (size_t)r * 512 + lane * 8) = packed;
}

// ---------------- RoPE in-place (R2: LDS sincos table — 32 sincos/block, not 544 powf+sincos) ----
__global__ __launch_bounds__(256) void k_rope(u16* __restrict__ qbuf, u16* __restrict__ kva) {
    int r = blockIdx.x;
    int s = r & 2047;
    int tid = threadIdx.x;
    __shared__ float cs_s[32], sn_s[32];
    if (tid < 32) {
        // freq = 10000^(-tid/32) = exp(-tid * ln(10000)/32)
        float freq = __expf(-0.28782313662425575f * (float)tid);
        float ang = (float)s * freq;
        float sn, cs;
        sincosf(ang, &sn, &cs);
        sn_s[tid] = sn; cs_s[tid] = cs;
    }
    __syncthreads();
    for (int t = tid; t < 544; t += 256) {
        int i = t & 31;
        float cs = cs_s[i], sn = sn_s[i];
        u16* p1;
        if (t < 512) {
            int h = t >> 5;
            p1 = qbuf + (size_t)r * 3072 + h * 192 + 128 + i;
        } else {
            p1 = kva + (size_t)r * 576 + 512 + i;
        }
        u16* p2 = p1 + 32;
        float x1 = bf2f(*p1), x2 = bf2f(*p2);
        *p1 = f2bf(x1 * cs - x2 * sn);
        *p2 = f2bf(x2 * cs + x1 * sn);
    }
}

// ---------------- Flash attention v3.1: block-cooperative, double-buffered LDS K/V ----------------
__global__ __launch_bounds__(256, 3) void k_attn(const u16* __restrict__ qbuf,
                                                 const u16* __restrict__ kv,
                                                 const u16* __restrict__ kva,
                                                 const u16* __restrict__ vt,
                                                 u16* __restrict__ attno) {
    int tid = threadIdx.x;
    int wave = tid >> 6, lane = tid & 63;
    int quad = lane >> 4, l15 = lane & 15;
    int hb = blockIdx.x;                 // 0..31
    int h = hb & 15, b = hb >> 4;
    int qb = 31 - (int)blockIdx.y;       // descending: longest blocks first
    int qg0 = qb * 64 + wave * 16;       // wave's first q-row
    int row = qg0 + l15;                 // this lane's q-row (S^T col)

    __shared__ __align__(16) u16 Kn[2][32 * 136];
    __shared__ __align__(16) u16 Kp[2][32 * 72];
    __shared__ __align__(16) u16 Vs[2][128 * 40];
    __shared__ __align__(16) u16 P[4][16 * 40];

    const u16* qrp = qbuf + ((size_t)(b * 2048) + qg0 + l15) * 3072 + h * 192;
    bf16x8 qf[6];
    for (int c = 0; c < 6; c++) qf[c] = *(const bf16x8*)&qrp[c * 32 + quad * 8];

    const floatx4 fzero = {0.f, 0.f, 0.f, 0.f};
    floatx4 o[8];
    for (int f = 0; f < 8; f++) o[f] = fzero;
    float lp = 0.f;

    const u16* kvb = kv  + (size_t)(b * 2048) * 4096 + h * 256;   // + key*4096 (k_nope)
    const u16* kpb = kva + (size_t)(b * 2048) * 576 + 512;        // + key*576  (roped k_pe)
    const u16* vtb = vt  + (size_t)(b * 16 + h) * 128 * 2048;     // + vd*2048 + key
    const float scale = 0.07216878364870323f;                     // 192^-0.5

    int nkt = qb * 2 + 2;                // ceil((qb*64+63+1)/32)

    // staging chunk maps (16B chunks)
    int kKey0 = tid >> 4,          kOff0 = (tid & 15) * 8;        // Kn: 16 chunks/row
    int kKey1 = (tid + 256) >> 4,  kOff1 = (tid & 15) * 8;
    int pKey  = tid >> 3,          pOff  = (tid & 7) * 8;         // Kp: 8 chunks/row
    int vRow0 = tid >> 2,          vOff0 = (tid & 3) * 8;         // Vs: 4 chunks/row (rows 0..63)
    int vRow1 = (tid + 256) >> 2,  vOff1 = (tid & 3) * 8;         //     rows 64..127

    // prologue: stage tile 0 into buffer 0
    {
        uint4 a = *(const uint4*)&kvb[(size_t)kKey0 * 4096 + kOff0];
        uint4 c = *(const uint4*)&kvb[(size_t)kKey1 * 4096 + kOff1];
        uint4 d = *(const uint4*)&kpb[(size_t)pKey * 576 + pOff];
        uint4 e = *(const uint4*)&vtb[(size_t)vRow0 * 2048 + vOff0];
        uint4 g = *(const uint4*)&vtb[(size_t)vRow1 * 2048 + vOff1];
        *(uint4*)&Kn[0][kKey0 * 136 + kOff0] = a;
        *(uint4*)&Kn[0][kKey1 * 136 + kOff1] = c;
        *(uint4*)&Kp[0][pKey * 72 + pOff] = d;
        *(uint4*)&Vs[0][vRow0 * 40 + vOff0] = e;
        *(uint4*)&Vs[0][vRow1 * 40 + vOff1] = g;
    }
    __syncthreads();

    for (int kt = 0; kt < nkt; kt++) {
        int cur = kt & 1;
        bool have = (kt + 1) < nkt;
        uint4 sA = {}, sB = {}, sC = {}, sD = {}, sE = {};
        if (have) {
            int kb = (kt + 1) * 32;
            sA = *(const uint4*)&kvb[(size_t)(kb + kKey0) * 4096 + kOff0];
            sB = *(const uint4*)&kvb[(size_t)(kb + kKey1) * 4096 + kOff1];
            sC = *(const uint4*)&kpb[(size_t)(kb + pKey) * 576 + pOff];
            sD = *(const uint4*)&vtb[(size_t)vRow0 * 2048 + kb + vOff0];
            sE = *(const uint4*)&vtb[(size_t)vRow1 * 2048 + kb + vOff1];
        }
        if (kt * 32 <= qg0 + 15) {       // tile intersects this wave's causal range
            bf16x8 vf[8];
            for (int f = 0; f < 8; f++)
                vf[f] = *(const bf16x8*)&Vs[cur][(f * 16 + l15) * 40 + quad * 8];
            floatx4 sc[2] = {fzero, fzero};
            for (int hf = 0; hf < 2; hf++) {
                const u16* kn = &Kn[cur][(hf * 16 + l15) * 136];
                const u16* kp = &Kp[cur][(hf * 16 + l15) * 72];
                for (int c = 0; c < 4; c++) {
                    bf16x8 kf = *(const bf16x8*)&kn[c * 32 + quad * 8];
                    sc[hf] = __builtin_amdgcn_mfma_f32_16x16x32_bf16(kf, qf[c], sc[hf], 0, 0, 0);
                }
                for (int c = 0; c < 2; c++) {
                    bf16x8 kf = *(const bf16x8*)&kp[c * 32 + quad * 8];
                    sc[hf] = __builtin_amdgcn_mfma_f32_16x16x32_bf16(kf, qf[4 + c], sc[hf], 0, 0, 0);
                }
            }
            asm volatile("" ::: "memory");
            for (int hf = 0; hf < 2; hf++) {
                int keyb = kt * 32 + hf * 16 + quad * 4;
                float p[4];
                for (int r = 0; r < 4; r++)
                    p[r] = (keyb + r <= row) ? __expf(sc[hf][r] * scale) : 0.f;
                lp += (p[0] + p[1]) + (p[2] + p[3]);
                unsigned d0 = (unsigned)f2bf(p[0]) | ((unsigned)f2bf(p[1]) << 16);
                unsigned d1 = (unsigned)f2bf(p[2]) | ((unsigned)f2bf(p[3]) << 16);
                uint2 pk = {d0, d1};
                *(uint2*)&P[wave][l15 * 40 + hf * 16 + quad * 4] = pk;
            }
            asm volatile("" ::: "memory");
            bf16x8 pa = *(const bf16x8*)&P[wave][l15 * 40 + quad * 8];
            asm volatile("" ::: "memory");
            for (int f = 0; f < 8; f++)
                o[f] = __builtin_amdgcn_mfma_f32_16x16x32_bf16(pa, vf[f], o[f], 0, 0, 0);
        }
        if (have) {
            int nb = cur ^ 1;
            *(uint4*)&Kn[nb][kKey0 * 136 + kOff0] = sA;
            *(uint4*)&Kn[nb][kKey1 * 136 + kOff1] = sB;
            *(uint4*)&Kp[nb][pKey * 72 + pOff] = sC;
            *(uint4*)&Vs[nb][vRow0 * 40 + vOff0] = sD;
            *(uint4*)&Vs[nb][vRow1 * 40 + vOff1] = sE;
        }
        __syncthreads();
    }

    // reduce l across quads (lanes sharing l15 hold partials over key-quads)
    lp += __shfl_xor(lp, 16, 64);
    lp += __shfl_xor(lp, 32, 64);
    float lrow[4];
    for (int r = 0; r < 4; r++) lrow[r] = __shfl(lp, quad * 4 + r, 64);
    for (int f = 0; f < 8; f++)
        for (int r = 0; r < 4; r++) {
            int orow = qg0 + quad * 4 + r;
            float val = o[f][r] / lrow[r];
            attno[((size_t)(b * 2048) + orow) * 2048 + h * 128 + f * 16 + l15] = f2bf(val);
        }
}

extern "C" void kernel_launch(void* const* d_in, const int* in_sizes, int n_in,
                              void* d_out, int out_size, void* d_ws, size_t ws_size,
                              hipStream_t stream) {
    const float* x_raw    = (const float*)d_in[0];
    const float* wq_raw   = (const float*)d_in[1];
    const float* wkva_raw = (const float*)d_in[2];
    const float* wkvb_raw = (const float*)d_in[3];
    const float* wo_raw   = (const float*)d_in[4];
    const float* kvs_raw  = (const float*)d_in[5];
    float* out = (float*)d_out;
    u16* ws = (u16*)d_ws;

    // ---- ws regions (u16 offsets); total 96,993,280 bytes (< proven 105.4 MB) ----
    const size_t O_ATT = 0;          // wq_t -> {ckv, wkvb_t} -> attno
    const size_t O_VT  = 8388608;    // x_bf -> vt
    const size_t O_QB  = 16777216;   // qbuf -> wo_t
    const size_t O_KVA = 29360128;   // kva
    const size_t O_KV  = 31719424;   // kv
    const size_t TOTAL_BYTES = 48496640ull * 2;
    if (ws_size < TOTAL_BYTES) return;   // diagnostic: zeros -> absmax 4.03125

    u16* wq_t   = ws + O_ATT;
    u16* wkva_t = ws + O_ATT;            // after GEMM1
    u16* ckv    = ws + O_ATT;            // after GEMM2
    u16* wkvb_t = ws + O_ATT + 2097152;
    u16* attno  = ws + O_ATT;            // after GEMM3
    u16* x_bf   = ws + O_VT;
    u16* vt     = ws + O_VT;             // after GEMM2
    u16* qbuf   = ws + O_QB;
    u16* wo_t   = ws + O_QB;             // after attn
    u16* kva    = ws + O_KVA;
    u16* kv     = ws + O_KV;

    k_conv_x<<<4096, 256, 0, stream>>>(x_raw, x_bf, 1048576);
    k_convT<<<dim3(64, 96), 256, 0, stream>>>(wq_raw, wq_t, 2048, 3072);

    k_gemm256<4, false><<<dim3(16, 12), 512, 0, stream>>>(x_bf, wq_t, qbuf, 2048, 3072);      // GEMM1

    k_convT<<<dim3(64, 20), 256, 0, stream>>>(wkva_raw, wkva_t, 2048, 576);
    k_gemm_bt<false><<<dim3(32, 5), 256, 0, stream>>>(x_bf, wkva_t, kva, 576, 2048, 576);     // GEMM2

    k_rmsnorm<<<4096, 64, 0, stream>>>(kva, kvs_raw, ckv);
    k_convT<<<dim3(16, 128), 256, 0, stream>>>(wkvb_raw, wkvb_t, 512, 4096);
    k_gemm256<4, false><<<dim3(16, 16), 512, 0, stream>>>(ckv, wkvb_t, kv, 512, 4096);        // GEMM3

    k_rope<<<4096, 256, 0, stream>>>(qbuf, kva);
    k_transpose_v<<<dim3(64, 4, 32), 256, 0, stream>>>(kv, vt);

    k_attn<<<dim3(32, 32), 256, 0, stream>>>(qbuf, kv, kva, vt, attno);

    k_convT<<<dim3(64, 64), 256, 0, stream>>>(wo_raw, wo_t, 2048, 2048);
    k_gemm256<2, true><<<dim3(16, 16), 512, 0, stream>>>(attno, wo_t, out, 2048, 2048);       // GEMM4 -> f32
}

// Round 3
// 404.723 us; speedup vs baseline: 1.1136x; 1.0789x over previous
//
#include <hip/hip_runtime.h>
#include <stdint.h>
#include <stddef.h>

typedef __bf16 bf16x8 __attribute__((ext_vector_type(8)));
typedef float floatx4 __attribute__((ext_vector_type(4)));
typedef unsigned short u16;

__device__ __forceinline__ float bf2f(u16 h) {
    unsigned u = ((unsigned)h) << 16;
    return __builtin_bit_cast(float, u);
}
__device__ __forceinline__ u16 f2bf(float f) {
    unsigned u = __builtin_bit_cast(unsigned, f);
    u += 0x7fffu + ((u >> 16) & 1u);   // round-to-nearest-even
    return (u16)(u >> 16);
}

// async global->LDS, 16B per lane; lds dest is wave-uniform base (+lane*16 implicit)
__device__ __forceinline__ void gload16(const void* g, void* l) {
    __builtin_amdgcn_global_load_lds(
        (const __attribute__((address_space(1))) uint32_t*)g,
        (__attribute__((address_space(3))) uint32_t*)l, 16, 0, 0);
}

// counted vmcnt waits (literal strings required)
__device__ __forceinline__ void wait_vm8() { asm volatile("s_waitcnt vmcnt(8)" ::: "memory"); }
__device__ __forceinline__ void wait_vm6() { asm volatile("s_waitcnt vmcnt(6)" ::: "memory"); }
__device__ __forceinline__ void wait_vm4() { asm volatile("s_waitcnt vmcnt(4)" ::: "memory"); }
__device__ __forceinline__ void wait_vm3() { asm volatile("s_waitcnt vmcnt(3)" ::: "memory"); }
__device__ __forceinline__ void wait_vm0() { asm volatile("s_waitcnt vmcnt(0)" ::: "memory"); }

// ---------------- x: f32 -> bf16, vectorized (8/thread) ----------------
__global__ __launch_bounds__(256) void k_conv_x(const float* __restrict__ in,
                                                u16* __restrict__ out, int n8) {
    int i = blockIdx.x * 256 + threadIdx.x;
    if (i >= n8) return;
    const float* f = in + (size_t)i * 8;
    unsigned o[4];
    for (int t = 0; t < 4; t++) {
        u16 lo = f2bf(f[2 * t]), hi = f2bf(f[2 * t + 1]);
        o[t] = (unsigned)lo | ((unsigned)hi << 16);
    }
    uint4 p = {o[0], o[1], o[2], o[3]};
    *(uint4*)&out[(size_t)i * 8] = p;
}

// ---------------- weight: f32 (K,N) -> bf16 transposed (Npad,K), zero pad ----------------
__global__ __launch_bounds__(256) void k_convT(const float* __restrict__ in,
                                               u16* __restrict__ out, int K, int N) {
    __shared__ u16 t[32][33];
    int k0 = blockIdx.x * 32, n0 = blockIdx.y * 32;
    int c = threadIdx.x & 31, r8 = threadIdx.x >> 5;
    for (int j = 0; j < 4; j++) {
        int row = r8 + j * 8;
        int n = n0 + c;
        t[row][c] = (n < N) ? f2bf(in[(size_t)(k0 + row) * N + n]) : (u16)0;
    }
    __syncthreads();
    for (int j = 0; j < 4; j++) {
        int row = r8 + j * 8;
        out[(size_t)(n0 + row) * K + k0 + c] = t[c][row];
    }
}

// ---------------- V transpose: kv(b*S, h*256+128+vd) -> vt[(b,h,vd), s] ----------------
__global__ __launch_bounds__(256) void k_transpose_v(const u16* __restrict__ kv,
                                                     u16* __restrict__ vt) {
    __shared__ u16 t[32][33];
    int bh = blockIdx.z;
    int s0 = blockIdx.x * 32, v0 = blockIdx.y * 32;
    int c = threadIdx.x & 31, r8 = threadIdx.x >> 5;
    int b = bh >> 4, h = bh & 15;
    for (int j = 0; j < 4; j++) {
        int s = s0 + r8 + j * 8;
        t[r8 + j * 8][c] = kv[(size_t)(b * 2048 + s) * 4096 + h * 256 + 128 + v0 + c];
    }
    __syncthreads();
    for (int j = 0; j < 4; j++) {
        int v = v0 + r8 + j * 8;
        vt[((size_t)bh * 128 + v) * 2048 + s0 + c] = t[c][r8 + j * 8];
    }
}

// ---------------- legacy MFMA GEMM (m97 structure) — kept for small/ragged N (GEMM2) ----------------
template <bool F32OUT>
__global__ __launch_bounds__(256) void k_gemm_bt(const u16* __restrict__ A,
                                                 const u16* __restrict__ BT,
                                                 void* __restrict__ Cout,
                                                 int N, int K, int ldc) {
    __shared__ __align__(16) u16 As[128 * 32];
    __shared__ __align__(16) u16 Bs[128 * 32];
    int tid = threadIdx.x;
    int lane = tid & 63, wave = tid >> 6;
    int quad = lane >> 4, l15 = lane & 15;
    size_t m0 = (size_t)blockIdx.x * 128, n0 = (size_t)blockIdx.y * 128;
    int wm = (wave >> 1) * 64, wn = (wave & 1) * 64;
    const floatx4 fzero = {0.f, 0.f, 0.f, 0.f};
    floatx4 acc[4][4];
    for (int i = 0; i < 4; i++)
        for (int j = 0; j < 4; j++) acc[i][j] = fzero;

    for (int k0 = 0; k0 < K; k0 += 32) {
        for (int i = 0; i < 2; i++) {
            int cid = i * 256 + wave * 64 + lane;
            int row = cid >> 2, kc = cid & 3;
            gload16(&A[(m0 + row) * K + k0 + kc * 8], &As[(size_t)(i * 256 + wave * 64) * 8]);
            gload16(&BT[(n0 + row) * K + k0 + kc * 8], &Bs[(size_t)(i * 256 + wave * 64) * 8]);
        }
        __syncthreads();
        bf16x8 af[4], bfr[4];
        for (int i = 0; i < 4; i++) af[i]  = *(const bf16x8*)&As[(wm + i * 16 + l15) * 32 + quad * 8];
        for (int j = 0; j < 4; j++) bfr[j] = *(const bf16x8*)&Bs[(wn + j * 16 + l15) * 32 + quad * 8];
        for (int i = 0; i < 4; i++)
            for (int j = 0; j < 4; j++)
                acc[i][j] = __builtin_amdgcn_mfma_f32_16x16x32_bf16(af[i], bfr[j], acc[i][j], 0, 0, 0);
        __syncthreads();
    }
    for (int i = 0; i < 4; i++)
        for (int j = 0; j < 4; j++) {
            int col = (int)n0 + wn + j * 16 + l15;
            if (col >= N) continue;
            for (int r = 0; r < 4; r++) {
                size_t row = m0 + wm + i * 16 + quad * 4 + r;
                if (F32OUT) ((float*)Cout)[row * ldc + col] = acc[i][j][r];
                else        ((u16*)Cout)[row * ldc + col] = f2bf(acc[i][j][r]);
            }
        }
}

// ---------------- 256xBN ring-pipelined GEMM (T1+T2+T4+T5, AITER-style): C = A * BT^T ----
// BM=256, BN=NWC*64. 512 thr = 8 waves; wave (wr,wc) = (w/NWC, w%NWC) owns
// (256/(8/NWC)) x 64 output. K processed in BK=32 subtiles; 4-slot LDS ring
// (slot = A 256x32 + B BN x 32 bf16), PREFETCH 3 SUBTILES AHEAD.
// Steady state per subtile: s_waitcnt vmcnt(2*CH) [oldest subtile landed; 2
// subtiles stay in flight] -> s_barrier -> ds_read frags -> STAGE(j+3) ->
// setprio(1) MFMA setprio(0). vmcnt NEVER 0 in the main loop; ONE barrier per
// subtile; NO __syncthreads in the loop (counted-vmcnt discipline, m218/T4).
// Race-free: a wave passing barrier j has issued MMA(j-1) whose lgkm waits
// imply its ds_reads of slot (j-1)&3 completed; STAGE(j+3) overwrites that
// slot only after the barrier.
// st_16x32 swizzle in 1KiB subtiles; gload_lds writes linear, global source
// inverse-swizzled (rule #21). Requires M%256==0, N%BN==0, K%32==0, K/32>=4.
template <int NWC, bool F32OUT>
__global__ __launch_bounds__(512, 2) void k_gemm256(const u16* __restrict__ A,
                                                    const u16* __restrict__ BT,
                                                    void* __restrict__ Cout,
                                                    int K, int ldc) {
    constexpr int MFR = 16 / (8 / NWC);     // A frags/wave: NWC=4 -> 8, NWC=2 -> 4
    constexpr int ACH = 2;                  // A 16B-chunks per thread per subtile
    constexpr int BCH = NWC / 2;            // B chunks per thread per subtile
    constexpr int SLOT = 8192 + NWC * 2048; // u16 per ring slot (A + B)
    __shared__ __align__(16) u16 RING[4][SLOT];
    int tid = threadIdx.x;
    int w = tid >> 6, lane = tid & 63;
    int l15 = lane & 15, quad = lane >> 4;
    int wr = w / NWC, wc = w % NWC;

    // XCD-aware swizzle (bijective: nwg % 8 == 0 at all call sites)
    int gx = gridDim.x;
    int nwg = gx * gridDim.y;
    int flat = blockIdx.y * gx + blockIdx.x;
    int cpx = nwg >> 3;
    int swz = (flat & 7) * cpx + (flat >> 3);
    int bx = swz % gx, by = swz / gx;
    size_t m0 = (size_t)bx * 256, n0 = (size_t)by * (NWC * 64);
    int NT = K >> 5;

    // staging maps: chunk = p*512 + tid fills subtile s=chunk>>6 at u16 (chunk&63)*8
    // linearly; inverse-swizzle to find the global (row,k) for that LDS spot.
    const u16* srcA[ACH];
    const u16* srcB[BCH];
    int ldsAb[ACH], ldsBb[BCH];   // wave-uniform LDS bases (u16)
#pragma unroll
    for (int p = 0; p < ACH; p++) {
        int chunk = p * 512 + tid;
        int s = chunk >> 6;
        int b = (chunk & 63) * 8;
        int bu = b ^ (((b >> 8) & 1) << 4);        // inverse st_16x32 (involution)
        int r = bu >> 5, c = bu & 31;
        srcA[p] = A + (m0 + s * 16 + r) * (size_t)K + c;
        ldsAb[p] = (p * 512 + w * 64) * 8;
    }
#pragma unroll
    for (int p = 0; p < BCH; p++) {
        int chunk = p * 512 + tid;
        int s = chunk >> 6;
        int b = (chunk & 63) * 8;
        int bu = b ^ (((b >> 8) & 1) << 4);
        int r = bu >> 5, c = bu & 31;
        srcB[p] = BT + (n0 + s * 16 + r) * (size_t)K + c;
        ldsBb[p] = 8192 + (p * 512 + w * 64) * 8;
    }

    // swizzled ds_read lane offset inside a 1KiB subtile
    const int swb = (l15 * 32 + quad * 8) ^ ((l15 >> 3) << 4);

    floatx4 acc[MFR][4];
    const floatx4 fzero = {0.f, 0.f, 0.f, 0.f};
#pragma unroll
    for (int i = 0; i < MFR; i++)
#pragma unroll
        for (int j = 0; j < 4; j++) acc[i][j] = fzero;

    bf16x8 aA[MFR], bB[4];

    auto STAGE = [&](int j) {
        int rs = j & 3;
        size_t ko = (size_t)j * 32;
        u16* ring = &RING[rs][0];
#pragma unroll
        for (int p = 0; p < ACH; p++) gload16(srcA[p] + ko, ring + ldsAb[p]);
#pragma unroll
        for (int p = 0; p < BCH; p++) gload16(srcB[p] + ko, ring + ldsBb[p]);
    };
    auto READ = [&](int rs) {
        const u16* ring = &RING[rs][0];
#pragma unroll
        for (int i2 = 0; i2 < MFR; i2++)
            aA[i2] = *(const bf16x8*)&ring[(wr * MFR + i2) * 512 + swb];
#pragma unroll
        for (int j2 = 0; j2 < 4; j2++)
            bB[j2] = *(const bf16x8*)&ring[8192 + (wc * 4 + j2) * 512 + swb];
    };
    auto MMA = [&]() {
        __builtin_amdgcn_s_setprio(1);
#pragma unroll
        for (int i2 = 0; i2 < MFR; i2++)
#pragma unroll
            for (int j2 = 0; j2 < 4; j2++)
                acc[i2][j2] = __builtin_amdgcn_mfma_f32_16x16x32_bf16(
                    aA[i2], bB[j2], acc[i2][j2], 0, 0, 0);
        __builtin_amdgcn_s_setprio(0);
    };

    // prologue: 3 subtiles in flight
    STAGE(0); STAGE(1); STAGE(2);

    int j = 0;
    for (; j + 3 < NT; j++) {
        if constexpr (NWC == 4) wait_vm8(); else wait_vm6();
        __builtin_amdgcn_s_barrier();
        __builtin_amdgcn_sched_barrier(0);
        READ(j & 3);
        STAGE(j + 3);
        __builtin_amdgcn_sched_barrier(0);
        MMA();
    }
    // tail: drain 2*CH -> CH -> 0
    {
        if constexpr (NWC == 4) wait_vm8(); else wait_vm6();
        __builtin_amdgcn_s_barrier();
        __builtin_amdgcn_sched_barrier(0);
        READ(j & 3); MMA(); j++;
    }
    {
        if constexpr (NWC == 4) wait_vm4(); else wait_vm3();
        __builtin_amdgcn_s_barrier();
        __builtin_amdgcn_sched_barrier(0);
        READ(j & 3); MMA(); j++;
    }
    {
        wait_vm0();
        __builtin_amdgcn_s_barrier();
        __builtin_amdgcn_sched_barrier(0);
        READ(j & 3); MMA();
    }

#pragma unroll
    for (int i = 0; i < MFR; i++)
#pragma unroll
        for (int j2 = 0; j2 < 4; j2++) {
            size_t col = n0 + wc * 64 + j2 * 16 + l15;
#pragma unroll
            for (int r = 0; r < 4; r++) {
                size_t row = m0 + (size_t)wr * (MFR * 16) + i * 16 + quad * 4 + r;
                if (F32OUT) ((float*)Cout)[row * ldc + col] = acc[i][j2][r];
                else        ((u16*)Cout)[row * ldc + col] = f2bf(acc[i][j2][r]);
            }
        }
}

// ---------------- RMSNorm over first 512 cols of kva rows -> ckv ----------------
__global__ __launch_bounds__(64) void k_rmsnorm(const u16* __restrict__ kva,
                                                const float* __restrict__ scl,
                                                u16* __restrict__ ckv) {
    int r = blockIdx.x, lane = threadIdx.x;
    const u16* row = kva + (size_t)r * 576 + lane * 8;
    uint4 raw = *(const uint4*)row;
    unsigned w[4] = {raw.x, raw.y, raw.z, raw.w};
    float f[8];
    float ss = 0.f;
    for (int t = 0; t < 4; t++) {
        f[2 * t]     = bf2f((u16)(w[t] & 0xffffu));
        f[2 * t + 1] = bf2f((u16)(w[t] >> 16));
        ss += f[2 * t] * f[2 * t] + f[2 * t + 1] * f[2 * t + 1];
    }
    for (int off = 1; off < 64; off <<= 1) ss += __shfl_xor(ss, off, 64);
    float rs = rsqrtf(ss * (1.f / 512.f) + 1e-6f);
    unsigned o[4];
    for (int t = 0; t < 4; t++) {
        u16 lo = f2bf(f[2 * t] * rs * scl[lane * 8 + 2 * t]);
        u16 hi = f2bf(f[2 * t + 1] * rs * scl[lane * 8 + 2 * t + 1]);
        o[t] = (unsigned)lo | ((unsigned)hi << 16);
    }
    uint4 packed = {o[0], o[1], o[2], o[3]};
    *(uint4*)(ckv + (size_t)r * 512 + lane * 8) = packed;
}

// ---------------- RoPE in-place (R3: vectorized uint4 pair loads, 2 rows/block) ----------------
__global__ __launch_bounds__(256) void k_rope(u16* __restrict__ qbuf, u16* __restrict__ kva) {
    int tid = threadIdx.x;
    int rloc = tid >> 7;              // 0..1: which of the block's 2 rows
    int task = tid & 127;             // 0..127, active < 68
    int r = blockIdx.x * 2 + rloc;
    __shared__ float cs_s[2][32], sn_s[2][32];
    if (tid < 64) {
        int rr = tid >> 5, i = tid & 31;
        int ss = (blockIdx.x * 2 + rr) & 2047;
        float freq = __expf(-0.28782313662425575f * (float)i);  // 10000^(-i/32)
        float ang = (float)ss * freq;
        float sn, cs;
        sincosf(ang, &sn, &cs);
        cs_s[rr][i] = cs; sn_s[rr][i] = sn;
    }
    __syncthreads();
    if (task < 68) {
        int rb = task >> 2, q = task & 3;   // rope-block (16 q-heads + 1 k), quarter
        u16* base = (rb < 16) ? qbuf + (size_t)r * 3072 + rb * 192 + 128
                              : kva + (size_t)r * 576 + 512;
        u16* p1 = base + q * 8;
        uint4 x1v = *(uint4*)p1;
        uint4 x2v = *(uint4*)(p1 + 32);
        unsigned w1[4] = {x1v.x, x1v.y, x1v.z, x1v.w};
        unsigned w2[4] = {x2v.x, x2v.y, x2v.z, x2v.w};
        unsigned o1[4], o2[4];
        for (int t2 = 0; t2 < 4; t2++) {
            float a1 = bf2f((u16)(w1[t2] & 0xffffu)), b1 = bf2f((u16)(w1[t2] >> 16));
            float a2 = bf2f((u16)(w2[t2] & 0xffffu)), b2 = bf2f((u16)(w2[t2] >> 16));
            int i0 = q * 8 + t2 * 2, i1 = i0 + 1;
            float c0 = cs_s[rloc][i0], s0 = sn_s[rloc][i0];
            float c1 = cs_s[rloc][i1], s1 = sn_s[rloc][i1];
            o1[t2] = (unsigned)f2bf(a1 * c0 - a2 * s0) | ((unsigned)f2bf(b1 * c1 - b2 * s1) << 16);
            o2[t2] = (unsigned)f2bf(a2 * c0 + a1 * s0) | ((unsigned)f2bf(b2 * c1 + b1 * s1) << 16);
        }
        uint4 y1 = {o1[0], o1[1], o1[2], o1[3]};
        uint4 y2 = {o2[0], o2[1], o2[2], o2[3]};
        *(uint4*)p1 = y1;
        *(uint4*)(p1 + 32) = y2;
    }
}

// ---------------- Flash attention v3.1: block-cooperative, double-buffered LDS K/V ----------------
__global__ __launch_bounds__(256, 3) void k_attn(const u16* __restrict__ qbuf,
                                                 const u16* __restrict__ kv,
                                                 const u16* __restrict__ kva,
                                                 const u16* __restrict__ vt,
                                                 u16* __restrict__ attno) {
    int tid = threadIdx.x;
    int wave = tid >> 6, lane = tid & 63;
    int quad = lane >> 4, l15 = lane & 15;
    int hb = blockIdx.x;                 // 0..31
    int h = hb & 15, b = hb >> 4;
    int qb = 31 - (int)blockIdx.y;       // descending: longest blocks first
    int qg0 = qb * 64 + wave * 16;       // wave's first q-row
    int row = qg0 + l15;                 // this lane's q-row (S^T col)

    __shared__ __align__(16) u16 Kn[2][32 * 136];
    __shared__ __align__(16) u16 Kp[2][32 * 72];
    __shared__ __align__(16) u16 Vs[2][128 * 40];
    __shared__ __align__(16) u16 P[4][16 * 40];

    const u16* qrp = qbuf + ((size_t)(b * 2048) + qg0 + l15) * 3072 + h * 192;
    bf16x8 qf[6];
    for (int c = 0; c < 6; c++) qf[c] = *(const bf16x8*)&qrp[c * 32 + quad * 8];

    const floatx4 fzero = {0.f, 0.f, 0.f, 0.f};
    floatx4 o[8];
    for (int f = 0; f < 8; f++) o[f] = fzero;
    float lp = 0.f;

    const u16* kvb = kv  + (size_t)(b * 2048) * 4096 + h * 256;   // + key*4096 (k_nope)
    const u16* kpb = kva + (size_t)(b * 2048) * 576 + 512;        // + key*576  (roped k_pe)
    const u16* vtb = vt  + (size_t)(b * 16 + h) * 128 * 2048;     // + vd*2048 + key
    const float scale = 0.07216878364870323f;                     // 192^-0.5

    int nkt = qb * 2 + 2;                // ceil((qb*64+63+1)/32)

    // staging chunk maps (16B chunks)
    int kKey0 = tid >> 4,          kOff0 = (tid & 15) * 8;        // Kn: 16 chunks/row
    int kKey1 = (tid + 256) >> 4,  kOff1 = (tid & 15) * 8;
    int pKey  = tid >> 3,          pOff  = (tid & 7) * 8;         // Kp: 8 chunks/row
    int vRow0 = tid >> 2,          vOff0 = (tid & 3) * 8;         // Vs: 4 chunks/row (rows 0..63)
    int vRow1 = (tid + 256) >> 2,  vOff1 = (tid & 3) * 8;         //     rows 64..127

    // prologue: stage tile 0 into buffer 0
    {
        uint4 a = *(const uint4*)&kvb[(size_t)kKey0 * 4096 + kOff0];
        uint4 c = *(const uint4*)&kvb[(size_t)kKey1 * 4096 + kOff1];
        uint4 d = *(const uint4*)&kpb[(size_t)pKey * 576 + pOff];
        uint4 e = *(const uint4*)&vtb[(size_t)vRow0 * 2048 + vOff0];
        uint4 g = *(const uint4*)&vtb[(size_t)vRow1 * 2048 + vOff1];
        *(uint4*)&Kn[0][kKey0 * 136 + kOff0] = a;
        *(uint4*)&Kn[0][kKey1 * 136 + kOff1] = c;
        *(uint4*)&Kp[0][pKey * 72 + pOff] = d;
        *(uint4*)&Vs[0][vRow0 * 40 + vOff0] = e;
        *(uint4*)&Vs[0][vRow1 * 40 + vOff1] = g;
    }
    __syncthreads();

    for (int kt = 0; kt < nkt; kt++) {
        int cur = kt & 1;
        bool have = (kt + 1) < nkt;
        uint4 sA = {}, sB = {}, sC = {}, sD = {}, sE = {};
        if (have) {
            int kb = (kt + 1) * 32;
            sA = *(const uint4*)&kvb[(size_t)(kb + kKey0) * 4096 + kOff0];
            sB = *(const uint4*)&kvb[(size_t)(kb + kKey1) * 4096 + kOff1];
            sC = *(const uint4*)&kpb[(size_t)(kb + pKey) * 576 + pOff];
            sD = *(const uint4*)&vtb[(size_t)vRow0 * 2048 + kb + vOff0];
            sE = *(const uint4*)&vtb[(size_t)vRow1 * 2048 + kb + vOff1];
        }
        if (kt * 32 <= qg0 + 15) {       // tile intersects this wave's causal range
            bf16x8 vf[8];
            for (int f = 0; f < 8; f++)
                vf[f] = *(const bf16x8*)&Vs[cur][(f * 16 + l15) * 40 + quad * 8];
            floatx4 sc[2] = {fzero, fzero};
            for (int hf = 0; hf < 2; hf++) {
                const u16* kn = &Kn[cur][(hf * 16 + l15) * 136];
                const u16* kp = &Kp[cur][(hf * 16 + l15) * 72];
                for (int c = 0; c < 4; c++) {
                    bf16x8 kf = *(const bf16x8*)&kn[c * 32 + quad * 8];
                    sc[hf] = __builtin_amdgcn_mfma_f32_16x16x32_bf16(kf, qf[c], sc[hf], 0, 0, 0);
                }
                for (int c = 0; c < 2; c++) {
                    bf16x8 kf = *(const bf16x8*)&kp[c * 32 + quad * 8];
                    sc[hf] = __builtin_amdgcn_mfma_f32_16x16x32_bf16(kf, qf[4 + c], sc[hf], 0, 0, 0);
                }
            }
            asm volatile("" ::: "memory");
            for (int hf = 0; hf < 2; hf++) {
                int keyb = kt * 32 + hf * 16 + quad * 4;
                float p[4];
                for (int r = 0; r < 4; r++)
                    p[r] = (keyb + r <= row) ? __expf(sc[hf][r] * scale) : 0.f;
                lp += (p[0] + p[1]) + (p[2] + p[3]);
                unsigned d0 = (unsigned)f2bf(p[0]) | ((unsigned)f2bf(p[1]) << 16);
                unsigned d1 = (unsigned)f2bf(p[2]) | ((unsigned)f2bf(p[3]) << 16);
                uint2 pk = {d0, d1};
                *(uint2*)&P[wave][l15 * 40 + hf * 16 + quad * 4] = pk;
            }
            asm volatile("" ::: "memory");
            bf16x8 pa = *(const bf16x8*)&P[wave][l15 * 40 + quad * 8];
            asm volatile("" ::: "memory");
            for (int f = 0; f < 8; f++)
                o[f] = __builtin_amdgcn_mfma_f32_16x16x32_bf16(pa, vf[f], o[f], 0, 0, 0);
        }
        if (have) {
            int nb = cur ^ 1;
            *(uint4*)&Kn[nb][kKey0 * 136 + kOff0] = sA;
            *(uint4*)&Kn[nb][kKey1 * 136 + kOff1] = sB;
            *(uint4*)&Kp[nb][pKey * 72 + pOff] = sC;
            *(uint4*)&Vs[nb][vRow0 * 40 + vOff0] = sD;
            *(uint4*)&Vs[nb][vRow1 * 40 + vOff1] = sE;
        }
        __syncthreads();
    }

    // reduce l across quads (lanes sharing l15 hold partials over key-quads)
    lp += __shfl_xor(lp, 16, 64);
    lp += __shfl_xor(lp, 32, 64);
    float lrow[4];
    for (int r = 0; r < 4; r++) lrow[r] = __shfl(lp, quad * 4 + r, 64);
    for (int f = 0; f < 8; f++)
        for (int r = 0; r < 4; r++) {
            int orow = qg0 + quad * 4 + r;
            float val = o[f][r] / lrow[r];
            attno[((size_t)(b * 2048) + orow) * 2048 + h * 128 + f * 16 + l15] = f2bf(val);
        }
}

extern "C" void kernel_launch(void* const* d_in, const int* in_sizes, int n_in,
                              void* d_out, int out_size, void* d_ws, size_t ws_size,
                              hipStream_t stream) {
    const float* x_raw    = (const float*)d_in[0];
    const float* wq_raw   = (const float*)d_in[1];
    const float* wkva_raw = (const float*)d_in[2];
    const float* wkvb_raw = (const float*)d_in[3];
    const float* wo_raw   = (const float*)d_in[4];
    const float* kvs_raw  = (const float*)d_in[5];
    float* out = (float*)d_out;
    u16* ws = (u16*)d_ws;

    // ---- ws regions (u16 offsets); total 96,993,280 bytes (< proven 105.4 MB) ----
    const size_t O_ATT = 0;          // wq_t -> {ckv, wkvb_t} -> attno
    const size_t O_VT  = 8388608;    // x_bf -> vt
    const size_t O_QB  = 16777216;   // qbuf -> wo_t
    const size_t O_KVA = 29360128;   // kva
    const size_t O_KV  = 31719424;   // kv
    const size_t TOTAL_BYTES = 48496640ull * 2;
    if (ws_size < TOTAL_BYTES) return;   // diagnostic: zeros -> absmax 4.03125

    u16* wq_t   = ws + O_ATT;
    u16* wkva_t = ws + O_ATT;            // after GEMM1
    u16* ckv    = ws + O_ATT;            // after GEMM2
    u16* wkvb_t = ws + O_ATT + 2097152;
    u16* attno  = ws + O_ATT;            // after GEMM3
    u16* x_bf   = ws + O_VT;
    u16* vt     = ws + O_VT;             // after GEMM2
    u16* qbuf   = ws + O_QB;
    u16* wo_t   = ws + O_QB;             // after attn
    u16* kva    = ws + O_KVA;
    u16* kv     = ws + O_KV;

    k_conv_x<<<4096, 256, 0, stream>>>(x_raw, x_bf, 1048576);
    k_convT<<<dim3(64, 96), 256, 0, stream>>>(wq_raw, wq_t, 2048, 3072);

    k_gemm256<4, false><<<dim3(16, 12), 512, 0, stream>>>(x_bf, wq_t, qbuf, 2048, 3072);      // GEMM1

    k_convT<<<dim3(64, 20), 256, 0, stream>>>(wkva_raw, wkva_t, 2048, 576);
    k_gemm_bt<false><<<dim3(32, 5), 256, 0, stream>>>(x_bf, wkva_t, kva, 576, 2048, 576);     // GEMM2

    k_rmsnorm<<<4096, 64, 0, stream>>>(kva, kvs_raw, ckv);
    k_convT<<<dim3(16, 128), 256, 0, stream>>>(wkvb_raw, wkvb_t, 512, 4096);
    k_gemm256<4, false><<<dim3(16, 16), 512, 0, stream>>>(ckv, wkvb_t, kv, 512, 4096);        // GEMM3

    k_rope<<<2048, 256, 0, stream>>>(qbuf, kva);
    k_transpose_v<<<dim3(64, 4, 32), 256, 0, stream>>>(kv, vt);

    k_attn<<<dim3(32, 32), 256, 0, stream>>>(qbuf, kv, kva, vt, attno);

    k_convT<<<dim3(64, 64), 256, 0, stream>>>(wo_raw, wo_t, 2048, 2048);
    k_gemm256<2, true><<<dim3(16, 16), 512, 0, stream>>>(attno, wo_t, out, 2048, 2048);       // GEMM4 -> f32
}

// Round 5
// 396.960 us; speedup vs baseline: 1.1354x; 1.0196x over previous
//
#include <hip/hip_runtime.h>
#include <stdint.h>
#include <stddef.h>

typedef __bf16 bf16x8 __attribute__((ext_vector_type(8)));
typedef float floatx4 __attribute__((ext_vector_type(4)));
typedef unsigned short u16;

__device__ __forceinline__ float bf2f(u16 h) {
    unsigned u = ((unsigned)h) << 16;
    return __builtin_bit_cast(float, u);
}
__device__ __forceinline__ u16 f2bf(float f) {
    unsigned u = __builtin_bit_cast(unsigned, f);
    u += 0x7fffu + ((u >> 16) & 1u);   // round-to-nearest-even
    return (u16)(u >> 16);
}

// async global->LDS, 16B per lane; lds dest is wave-uniform base (+lane*16 implicit)
__device__ __forceinline__ void gload16(const void* g, void* l) {
    __builtin_amdgcn_global_load_lds(
        (const __attribute__((address_space(1))) uint32_t*)g,
        (__attribute__((address_space(3))) uint32_t*)l, 16, 0, 0);
}

// counted vmcnt waits (literal strings required)
__device__ __forceinline__ void wait_vm8() { asm volatile("s_waitcnt vmcnt(8)" ::: "memory"); }
__device__ __forceinline__ void wait_vm6() { asm volatile("s_waitcnt vmcnt(6)" ::: "memory"); }
__device__ __forceinline__ void wait_vm4() { asm volatile("s_waitcnt vmcnt(4)" ::: "memory"); }
__device__ __forceinline__ void wait_vm3() { asm volatile("s_waitcnt vmcnt(3)" ::: "memory"); }
__device__ __forceinline__ void wait_vm0() { asm volatile("s_waitcnt vmcnt(0)" ::: "memory"); }

// ---------------- x: f32 -> bf16, vectorized (8/thread) ----------------
__global__ __launch_bounds__(256) void k_conv_x(const float* __restrict__ in,
                                                u16* __restrict__ out, int n8) {
    int i = blockIdx.x * 256 + threadIdx.x;
    if (i >= n8) return;
    const float* f = in + (size_t)i * 8;
    unsigned o[4];
    for (int t = 0; t < 4; t++) {
        u16 lo = f2bf(f[2 * t]), hi = f2bf(f[2 * t + 1]);
        o[t] = (unsigned)lo | ((unsigned)hi << 16);
    }
    uint4 p = {o[0], o[1], o[2], o[3]};
    *(uint4*)&out[(size_t)i * 8] = p;
}

// ---------------- weight: f32 (K,N) -> bf16 transposed (Npad,K), zero pad ----------------
__global__ __launch_bounds__(256) void k_convT(const float* __restrict__ in,
                                               u16* __restrict__ out, int K, int N) {
    __shared__ u16 t[32][33];
    int k0 = blockIdx.x * 32, n0 = blockIdx.y * 32;
    int c = threadIdx.x & 31, r8 = threadIdx.x >> 5;
    for (int j = 0; j < 4; j++) {
        int row = r8 + j * 8;
        int n = n0 + c;
        t[row][c] = (n < N) ? f2bf(in[(size_t)(k0 + row) * N + n]) : (u16)0;
    }
    __syncthreads();
    for (int j = 0; j < 4; j++) {
        int row = r8 + j * 8;
        out[(size_t)(n0 + row) * K + k0 + c] = t[c][row];
    }
}

// ---------------- V transpose: kv(b*S, h*256+128+vd) -> vt[(b,h,vd), s] ----------------
__global__ __launch_bounds__(256) void k_transpose_v(const u16* __restrict__ kv,
                                                     u16* __restrict__ vt) {
    __shared__ u16 t[32][33];
    int bh = blockIdx.z;
    int s0 = blockIdx.x * 32, v0 = blockIdx.y * 32;
    int c = threadIdx.x & 31, r8 = threadIdx.x >> 5;
    int b = bh >> 4, h = bh & 15;
    for (int j = 0; j < 4; j++) {
        int s = s0 + r8 + j * 8;
        t[r8 + j * 8][c] = kv[(size_t)(b * 2048 + s) * 4096 + h * 256 + 128 + v0 + c];
    }
    __syncthreads();
    for (int j = 0; j < 4; j++) {
        int v = v0 + r8 + j * 8;
        vt[((size_t)bh * 128 + v) * 2048 + s0 + c] = t[c][r8 + j * 8];
    }
}

// ---------------- 256xBN ring-pipelined GEMM (T1+T2+T4+T5, AITER-style): C = A * BT^T ----
// BM=256, BN=NWC*64. 512 thr = 8 waves; wave (wr,wc) = (w/NWC, w%NWC) owns
// (256/(8/NWC)) x 64 output. K processed in BK=32 subtiles; 4-slot LDS ring
// (slot = A 256x32 + B BN x 32 bf16), PREFETCH 3 SUBTILES AHEAD.
// Steady state per subtile: s_waitcnt vmcnt(2*CH) -> s_barrier -> ds_read frags
// -> STAGE(j+3) -> setprio(1) MFMA setprio(0). vmcnt NEVER 0 in the main loop;
// ONE barrier per subtile; NO __syncthreads in the loop (m218/T4 discipline).
// st_16x32 swizzle in 1KiB subtiles; gload_lds writes linear, global source
// inverse-swizzled (rule #21). Requires M%256==0, N%BN==0, K%32==0, K/32>=4.
// MODE: 0 = u16 out (C0, ldc); 1 = f32 out (C0, ldc);
//       2 = split store: col<3072 -> C0 u16 ldc 3072; 3072<=col<3648 -> C1 u16 ldc 576.
template <int NWC, int MODE>
__global__ __launch_bounds__(512, 2) void k_gemm256(const u16* __restrict__ A,
                                                    const u16* __restrict__ BT,
                                                    void* __restrict__ C0,
                                                    void* __restrict__ C1,
                                                    int K, int ldc) {
    constexpr int MFR = 16 / (8 / NWC);     // A frags/wave: NWC=4 -> 8, NWC=2 -> 4
    constexpr int ACH = 2;                  // A 16B-chunks per thread per subtile
    constexpr int BCH = NWC / 2;            // B chunks per thread per subtile
    constexpr int SLOT = 8192 + NWC * 2048; // u16 per ring slot (A + B)
    __shared__ __align__(16) u16 RING[4][SLOT];
    int tid = threadIdx.x;
    int w = tid >> 6, lane = tid & 63;
    int l15 = lane & 15, quad = lane >> 4;
    int wr = w / NWC, wc = w % NWC;

    // XCD-aware swizzle (bijective: nwg % 8 == 0 at all call sites)
    int gx = gridDim.x;
    int nwg = gx * gridDim.y;
    int flat = blockIdx.y * gx + blockIdx.x;
    int cpx = nwg >> 3;
    int swz = (flat & 7) * cpx + (flat >> 3);
    int bx = swz % gx, by = swz / gx;
    size_t m0 = (size_t)bx * 256, n0 = (size_t)by * (NWC * 64);
    int NT = K >> 5;

    // staging maps: chunk = p*512 + tid fills subtile s=chunk>>6 at u16 (chunk&63)*8
    // linearly; inverse-swizzle to find the global (row,k) for that LDS spot.
    const u16* srcA[ACH];
    const u16* srcB[BCH];
    int ldsAb[ACH], ldsBb[BCH];   // wave-uniform LDS bases (u16)
#pragma unroll
    for (int p = 0; p < ACH; p++) {
        int chunk = p * 512 + tid;
        int s = chunk >> 6;
        int b = (chunk & 63) * 8;
        int bu = b ^ (((b >> 8) & 1) << 4);        // inverse st_16x32 (involution)
        int r = bu >> 5, c = bu & 31;
        srcA[p] = A + (m0 + s * 16 + r) * (size_t)K + c;
        ldsAb[p] = (p * 512 + w * 64) * 8;
    }
#pragma unroll
    for (int p = 0; p < BCH; p++) {
        int chunk = p * 512 + tid;
        int s = chunk >> 6;
        int b = (chunk & 63) * 8;
        int bu = b ^ (((b >> 8) & 1) << 4);
        int r = bu >> 5, c = bu & 31;
        srcB[p] = BT + (n0 + s * 16 + r) * (size_t)K + c;
        ldsBb[p] = 8192 + (p * 512 + w * 64) * 8;
    }

    // swizzled ds_read lane offset inside a 1KiB subtile
    const int swb = (l15 * 32 + quad * 8) ^ ((l15 >> 3) << 4);

    floatx4 acc[MFR][4];
    const floatx4 fzero = {0.f, 0.f, 0.f, 0.f};
#pragma unroll
    for (int i = 0; i < MFR; i++)
#pragma unroll
        for (int j = 0; j < 4; j++) acc[i][j] = fzero;

    bf16x8 aA[MFR], bB[4];

    auto STAGE = [&](int j) {
        int rs = j & 3;
        size_t ko = (size_t)j * 32;
        u16* ring = &RING[rs][0];
#pragma unroll
        for (int p = 0; p < ACH; p++) gload16(srcA[p] + ko, ring + ldsAb[p]);
#pragma unroll
        for (int p = 0; p < BCH; p++) gload16(srcB[p] + ko, ring + ldsBb[p]);
    };
    auto READ = [&](int rs) {
        const u16* ring = &RING[rs][0];
#pragma unroll
        for (int i2 = 0; i2 < MFR; i2++)
            aA[i2] = *(const bf16x8*)&ring[(wr * MFR + i2) * 512 + swb];
#pragma unroll
        for (int j2 = 0; j2 < 4; j2++)
            bB[j2] = *(const bf16x8*)&ring[8192 + (wc * 4 + j2) * 512 + swb];
    };
    auto MMA = [&]() {
        __builtin_amdgcn_s_setprio(1);
#pragma unroll
        for (int i2 = 0; i2 < MFR; i2++)
#pragma unroll
            for (int j2 = 0; j2 < 4; j2++)
                acc[i2][j2] = __builtin_amdgcn_mfma_f32_16x16x32_bf16(
                    aA[i2], bB[j2], acc[i2][j2], 0, 0, 0);
        __builtin_amdgcn_s_setprio(0);
    };

    // prologue: 3 subtiles in flight
    STAGE(0); STAGE(1); STAGE(2);

    int j = 0;
    for (; j + 3 < NT; j++) {
        if constexpr (NWC == 4) wait_vm8(); else wait_vm6();
        __builtin_amdgcn_s_barrier();
        __builtin_amdgcn_sched_barrier(0);
        READ(j & 3);
        STAGE(j + 3);
        __builtin_amdgcn_sched_barrier(0);
        MMA();
    }
    // tail: drain 2*CH -> CH -> 0
    {
        if constexpr (NWC == 4) wait_vm8(); else wait_vm6();
        __builtin_amdgcn_s_barrier();
        __builtin_amdgcn_sched_barrier(0);
        READ(j & 3); MMA(); j++;
    }
    {
        if constexpr (NWC == 4) wait_vm4(); else wait_vm3();
        __builtin_amdgcn_s_barrier();
        __builtin_amdgcn_sched_barrier(0);
        READ(j & 3); MMA(); j++;
    }
    {
        wait_vm0();
        __builtin_amdgcn_s_barrier();
        __builtin_amdgcn_sched_barrier(0);
        READ(j & 3); MMA();
    }

#pragma unroll
    for (int i = 0; i < MFR; i++)
#pragma unroll
        for (int j2 = 0; j2 < 4; j2++) {
            size_t col = n0 + wc * 64 + j2 * 16 + l15;
#pragma unroll
            for (int r = 0; r < 4; r++) {
                size_t row = m0 + (size_t)wr * (MFR * 16) + i * 16 + quad * 4 + r;
                if constexpr (MODE == 0) {
                    ((u16*)C0)[row * ldc + col] = f2bf(acc[i][j2][r]);
                } else if constexpr (MODE == 1) {
                    ((float*)C0)[row * ldc + col] = acc[i][j2][r];
                } else {
                    if (col < 3072)
                        ((u16*)C0)[row * 3072 + col] = f2bf(acc[i][j2][r]);
                    else if (col < 3648)
                        ((u16*)C1)[row * 576 + (col - 3072)] = f2bf(acc[i][j2][r]);
                }
            }
        }
}

// ---------------- RMSNorm over first 512 cols of kva rows -> ckv ----------------
__global__ __launch_bounds__(64) void k_rmsnorm(const u16* __restrict__ kva,
                                                const float* __restrict__ scl,
                                                u16* __restrict__ ckv) {
    int r = blockIdx.x, lane = threadIdx.x;
    const u16* row = kva + (size_t)r * 576 + lane * 8;
    uint4 raw = *(const uint4*)row;
    unsigned w[4] = {raw.x, raw.y, raw.z, raw.w};
    float f[8];
    float ss = 0.f;
    for (int t = 0; t < 4; t++) {
        f[2 * t]     = bf2f((u16)(w[t] & 0xffffu));
        f[2 * t + 1] = bf2f((u16)(w[t] >> 16));
        ss += f[2 * t] * f[2 * t] + f[2 * t + 1] * f[2 * t + 1];
    }
    for (int off = 1; off < 64; off <<= 1) ss += __shfl_xor(ss, off, 64);
    float rs = rsqrtf(ss * (1.f / 512.f) + 1e-6f);
    unsigned o[4];
    for (int t = 0; t < 4; t++) {
        u16 lo = f2bf(f[2 * t] * rs * scl[lane * 8 + 2 * t]);
        u16 hi = f2bf(f[2 * t + 1] * rs * scl[lane * 8 + 2 * t + 1]);
        o[t] = (unsigned)lo | ((unsigned)hi << 16);
    }
    uint4 packed = {o[0], o[1], o[2], o[3]};
    *(uint4*)(ckv + (size_t)r * 512 + lane * 8) = packed;
}

// ---------------- RoPE in-place (vectorized uint4 pair loads, 2 rows/block) ----------------
__global__ __launch_bounds__(256) void k_rope(u16* __restrict__ qbuf, u16* __restrict__ kva) {
    int tid = threadIdx.x;
    int rloc = tid >> 7;              // 0..1: which of the block's 2 rows
    int task = tid & 127;             // 0..127, active < 68
    int r = blockIdx.x * 2 + rloc;
    __shared__ float cs_s[2][32], sn_s[2][32];
    if (tid < 64) {
        int rr = tid >> 5, i = tid & 31;
        int ss = (blockIdx.x * 2 + rr) & 2047;
        float freq = __expf(-0.28782313662425575f * (float)i);  // 10000^(-i/32)
        float ang = (float)ss * freq;
        float sn, cs;
        sincosf(ang, &sn, &cs);
        cs_s[rr][i] = cs; sn_s[rr][i] = sn;
    }
    __syncthreads();
    if (task < 68) {
        int rb = task >> 2, q = task & 3;   // rope-block (16 q-heads + 1 k), quarter
        u16* base = (rb < 16) ? qbuf + (size_t)r * 3072 + rb * 192 + 128
                              : kva + (size_t)r * 576 + 512;
        u16* p1 = base + q * 8;
        uint4 x1v = *(uint4*)p1;
        uint4 x2v = *(uint4*)(p1 + 32);
        unsigned w1[4] = {x1v.x, x1v.y, x1v.z, x1v.w};
        unsigned w2[4] = {x2v.x, x2v.y, x2v.z, x2v.w};
        unsigned o1[4], o2[4];
        for (int t2 = 0; t2 < 4; t2++) {
            float a1 = bf2f((u16)(w1[t2] & 0xffffu)), b1 = bf2f((u16)(w1[t2] >> 16));
            float a2 = bf2f((u16)(w2[t2] & 0xffffu)), b2 = bf2f((u16)(w2[t2] >> 16));
            int i0 = q * 8 + t2 * 2, i1 = i0 + 1;
            float c0 = cs_s[rloc][i0], s0 = sn_s[rloc][i0];
            float c1 = cs_s[rloc][i1], s1 = sn_s[rloc][i1];
            o1[t2] = (unsigned)f2bf(a1 * c0 - a2 * s0) | ((unsigned)f2bf(b1 * c1 - b2 * s1) << 16);
            o2[t2] = (unsigned)f2bf(a2 * c0 + a1 * s0) | ((unsigned)f2bf(b2 * c1 + b1 * s1) << 16);
        }
        uint4 y1 = {o1[0], o1[1], o1[2], o1[3]};
        uint4 y2 = {o2[0], o2[1], o2[2], o2[3]};
        *(uint4*)p1 = y1;
        *(uint4*)(p1 + 32) = y2;
    }
}

// ---------------- Flash attention v3.1: block-cooperative, double-buffered LDS K/V ----------------
__global__ __launch_bounds__(256, 3) void k_attn(const u16* __restrict__ qbuf,
                                                 const u16* __restrict__ kv,
                                                 const u16* __restrict__ kva,
                                                 const u16* __restrict__ vt,
                                                 u16* __restrict__ attno) {
    int tid = threadIdx.x;
    int wave = tid >> 6, lane = tid & 63;
    int quad = lane >> 4, l15 = lane & 15;
    int hb = blockIdx.x;                 // 0..31
    int h = hb & 15, b = hb >> 4;
    int qb = 31 - (int)blockIdx.y;       // descending: longest blocks first
    int qg0 = qb * 64 + wave * 16;       // wave's first q-row
    int row = qg0 + l15;                 // this lane's q-row (S^T col)

    __shared__ __align__(16) u16 Kn[2][32 * 136];
    __shared__ __align__(16) u16 Kp[2][32 * 72];
    __shared__ __align__(16) u16 Vs[2][128 * 40];
    __shared__ __align__(16) u16 P[4][16 * 40];

    const u16* qrp = qbuf + ((size_t)(b * 2048) + qg0 + l15) * 3072 + h * 192;
    bf16x8 qf[6];
    for (int c = 0; c < 6; c++) qf[c] = *(const bf16x8*)&qrp[c * 32 + quad * 8];

    const floatx4 fzero = {0.f, 0.f, 0.f, 0.f};
    floatx4 o[8];
    for (int f = 0; f < 8; f++) o[f] = fzero;
    float lp = 0.f;

    const u16* kvb = kv  + (size_t)(b * 2048) * 4096 + h * 256;   // + key*4096 (k_nope)
    const u16* kpb = kva + (size_t)(b * 2048) * 576 + 512;        // + key*576  (roped k_pe)
    const u16* vtb = vt  + (size_t)(b * 16 + h) * 128 * 2048;     // + vd*2048 + key
    const float scale = 0.07216878364870323f;                     // 192^-0.5

    int nkt = qb * 2 + 2;                // ceil((qb*64+63+1)/32)

    // staging chunk maps (16B chunks)
    int kKey0 = tid >> 4,          kOff0 = (tid & 15) * 8;        // Kn: 16 chunks/row
    int kKey1 = (tid + 256) >> 4,  kOff1 = (tid & 15) * 8;
    int pKey  = tid >> 3,          pOff  = (tid & 7) * 8;         // Kp: 8 chunks/row
    int vRow0 = tid >> 2,          vOff0 = (tid & 3) * 8;         // Vs: 4 chunks/row (rows 0..63)
    int vRow1 = (tid + 256) >> 2,  vOff1 = (tid & 3) * 8;         //     rows 64..127

    // prologue: stage tile 0 into buffer 0
    {
        uint4 a = *(const uint4*)&kvb[(size_t)kKey0 * 4096 + kOff0];
        uint4 c = *(const uint4*)&kvb[(size_t)kKey1 * 4096 + kOff1];
        uint4 d = *(const uint4*)&kpb[(size_t)pKey * 576 + pOff];
        uint4 e = *(const uint4*)&vtb[(size_t)vRow0 * 2048 + vOff0];
        uint4 g = *(const uint4*)&vtb[(size_t)vRow1 * 2048 + vOff1];
        *(uint4*)&Kn[0][kKey0 * 136 + kOff0] = a;
        *(uint4*)&Kn[0][kKey1 * 136 + kOff1] = c;
        *(uint4*)&Kp[0][pKey * 72 + pOff] = d;
        *(uint4*)&Vs[0][vRow0 * 40 + vOff0] = e;
        *(uint4*)&Vs[0][vRow1 * 40 + vOff1] = g;
    }
    __syncthreads();

    for (int kt = 0; kt < nkt; kt++) {
        int cur = kt & 1;
        bool have = (kt + 1) < nkt;
        uint4 sA = {}, sB = {}, sC = {}, sD = {}, sE = {};
        if (have) {
            int kb = (kt + 1) * 32;
            sA = *(const uint4*)&kvb[(size_t)(kb + kKey0) * 4096 + kOff0];
            sB = *(const uint4*)&kvb[(size_t)(kb + kKey1) * 4096 + kOff1];
            sC = *(const uint4*)&kpb[(size_t)(kb + pKey) * 576 + pOff];
            sD = *(const uint4*)&vtb[(size_t)vRow0 * 2048 + kb + vOff0];
            sE = *(const uint4*)&vtb[(size_t)vRow1 * 2048 + kb + vOff1];
        }
        if (kt * 32 <= qg0 + 15) {       // tile intersects this wave's causal range
            bf16x8 vf[8];
            for (int f = 0; f < 8; f++)
                vf[f] = *(const bf16x8*)&Vs[cur][(f * 16 + l15) * 40 + quad * 8];
            floatx4 sc[2] = {fzero, fzero};
            __builtin_amdgcn_s_setprio(1);
            for (int hf = 0; hf < 2; hf++) {
                const u16* kn = &Kn[cur][(hf * 16 + l15) * 136];
                const u16* kp = &Kp[cur][(hf * 16 + l15) * 72];
                for (int c = 0; c < 4; c++) {
                    bf16x8 kf = *(const bf16x8*)&kn[c * 32 + quad * 8];
                    sc[hf] = __builtin_amdgcn_mfma_f32_16x16x32_bf16(kf, qf[c], sc[hf], 0, 0, 0);
                }
                for (int c = 0; c < 2; c++) {
                    bf16x8 kf = *(const bf16x8*)&kp[c * 32 + quad * 8];
                    sc[hf] = __builtin_amdgcn_mfma_f32_16x16x32_bf16(kf, qf[4 + c], sc[hf], 0, 0, 0);
                }
            }
            __builtin_amdgcn_s_setprio(0);
            asm volatile("" ::: "memory");
            for (int hf = 0; hf < 2; hf++) {
                int keyb = kt * 32 + hf * 16 + quad * 4;
                float p[4];
                for (int r = 0; r < 4; r++)
                    p[r] = (keyb + r <= row) ? __expf(sc[hf][r] * scale) : 0.f;
                lp += (p[0] + p[1]) + (p[2] + p[3]);
                unsigned d0 = (unsigned)f2bf(p[0]) | ((unsigned)f2bf(p[1]) << 16);
                unsigned d1 = (unsigned)f2bf(p[2]) | ((unsigned)f2bf(p[3]) << 16);
                uint2 pk = {d0, d1};
                *(uint2*)&P[wave][l15 * 40 + hf * 16 + quad * 4] = pk;
            }
            asm volatile("" ::: "memory");
            bf16x8 pa = *(const bf16x8*)&P[wave][l15 * 40 + quad * 8];
            asm volatile("" ::: "memory");
            __builtin_amdgcn_s_setprio(1);
            for (int f = 0; f < 8; f++)
                o[f] = __builtin_amdgcn_mfma_f32_16x16x32_bf16(pa, vf[f], o[f], 0, 0, 0);
            __builtin_amdgcn_s_setprio(0);
        }
        if (have) {
            int nb = cur ^ 1;
            *(uint4*)&Kn[nb][kKey0 * 136 + kOff0] = sA;
            *(uint4*)&Kn[nb][kKey1 * 136 + kOff1] = sB;
            *(uint4*)&Kp[nb][pKey * 72 + pOff] = sC;
            *(uint4*)&Vs[nb][vRow0 * 40 + vOff0] = sD;
            *(uint4*)&Vs[nb][vRow1 * 40 + vOff1] = sE;
        }
        __syncthreads();
    }

    // reduce l across quads (lanes sharing l15 hold partials over key-quads)
    lp += __shfl_xor(lp, 16, 64);
    lp += __shfl_xor(lp, 32, 64);
    float lrow[4];
    for (int r = 0; r < 4; r++) lrow[r] = __shfl(lp, quad * 4 + r, 64);
    for (int f = 0; f < 8; f++)
        for (int r = 0; r < 4; r++) {
            int orow = qg0 + quad * 4 + r;
            float val = o[f][r] / lrow[r];
            attno[((size_t)(b * 2048) + orow) * 2048 + h * 128 + f * 16 + l15] = f2bf(val);
        }
}

extern "C" void kernel_launch(void* const* d_in, const int* in_sizes, int n_in,
                              void* d_out, int out_size, void* d_ws, size_t ws_size,
                              hipStream_t stream) {
    const float* x_raw    = (const float*)d_in[0];
    const float* wq_raw   = (const float*)d_in[1];
    const float* wkva_raw = (const float*)d_in[2];
    const float* wkvb_raw = (const float*)d_in[3];
    const float* wo_raw   = (const float*)d_in[4];
    const float* kvs_raw  = (const float*)d_in[5];
    float* out = (float*)d_out;
    u16* ws = (u16*)d_ws;

    // ---- ws regions (u16 offsets) ----
    const size_t O_ATT = 0;          // g12bt (3712x2048=7.60M u16) -> {ckv, wkvb_t} -> attno
    const size_t O_VT  = 8388608;    // x_bf -> vt
    const size_t O_QB  = 16777216;   // qbuf -> wo_t
    const size_t O_KVA = 29360128;   // kva
    const size_t O_KV  = 31719424;   // kv
    const size_t TOTAL_BYTES = 48496640ull * 2;
    if (ws_size < TOTAL_BYTES) return;   // diagnostic: zeros -> absmax 4.03125

    u16* g12bt  = ws + O_ATT;            // merged [wq_t (3072 rows); wkva_t (576+pad rows)]
    u16* ckv    = ws + O_ATT;            // after GEMM12
    u16* wkvb_t = ws + O_ATT + 2097152;
    u16* attno  = ws + O_ATT;            // after GEMM3
    u16* x_bf   = ws + O_VT;
    u16* vt     = ws + O_VT;             // after GEMM12
    u16* qbuf   = ws + O_QB;
    u16* wo_t   = ws + O_QB;             // after attn
    u16* kva    = ws + O_KVA;
    u16* kv     = ws + O_KV;

    k_conv_x<<<4096, 256, 0, stream>>>(x_raw, x_bf, 1048576);
    // merged BT: rows 0..3071 = wq^T, rows 3072..3711 = wkva^T (zero-pad to 3712 via convT)
    k_convT<<<dim3(64, 96), 256, 0, stream>>>(wq_raw, g12bt, 2048, 3072);
    k_convT<<<dim3(64, 20), 256, 0, stream>>>(wkva_raw, g12bt + (size_t)3072 * 2048, 2048, 576);

    // GEMM1+2 fused: N=3712 (29x128), split store -> qbuf (cols<3072), kva (cols 3072..3647)
    k_gemm256<2, 2><<<dim3(16, 29), 512, 0, stream>>>(x_bf, g12bt, qbuf, kva, 2048, 0);

    k_rmsnorm<<<4096, 64, 0, stream>>>(kva, kvs_raw, ckv);
    k_convT<<<dim3(16, 128), 256, 0, stream>>>(wkvb_raw, wkvb_t, 512, 4096);
    k_gemm256<4, 0><<<dim3(16, 16), 512, 0, stream>>>(ckv, wkvb_t, kv, nullptr, 512, 4096);   // GEMM3

    k_rope<<<2048, 256, 0, stream>>>(qbuf, kva);
    k_transpose_v<<<dim3(64, 4, 32), 256, 0, stream>>>(kv, vt);

    k_attn<<<dim3(32, 32), 256, 0, stream>>>(qbuf, kv, kva, vt, attno);

    k_convT<<<dim3(64, 64), 256, 0, stream>>>(wo_raw, wo_t, 2048, 2048);
    k_gemm256<2, 1><<<dim3(16, 16), 512, 0, stream>>>(attno, wo_t, out, nullptr, 2048, 2048); // GEMM4 -> f32
}